// Round 21
// baseline (305.417 us; speedup 1.0000x reference)
//
#include <hip/hip_runtime.h>
#include <math.h>

#define B_N 32768
#define A_N 6
#define H_N 256
#define D_N 128
#define K_N 2048
#define MU_CERT 2e-8f   // >= 4x the bf16-split approx error bound (~5e-9)
#define CB_N 2          // code-dimension split of vq_mfma
#define CPC (K_N / CB_N)

typedef __attribute__((ext_vector_type(8))) short bf16x8;
typedef __attribute__((ext_vector_type(4))) float f32x4;

// Block compiler from contracting a*a into subsequent adds (np computes z*z array, then sums it)
__device__ __forceinline__ float sqf(float v) {
    float s = v * v;
    asm volatile("" : "+v"(s));
    return s;
}

// numpy pairwise_sum for n=128 contiguous fp32: 8 accumulators stride-8 + fixed 3-level tree.
// Bitwise replication of np.sum(x*x, axis=-1). PROTECTED SEMANTICS: do not alter the add order.
__device__ __forceinline__ float np_sumsq_128(const float* __restrict__ p)
{
    float r[8];
#pragma unroll
    for (int j = 0; j < 8; j++) r[j] = sqf(p[j]);
#pragma unroll
    for (int i = 8; i < 128; i += 8) {
#pragma unroll
        for (int j = 0; j < 8; j++) r[j] = r[j] + sqf(p[i + j]);
    }
    return ((r[0] + r[1]) + (r[2] + r[3])) + ((r[4] + r[5]) + (r[6] + r[7]));
}

// ---------------- bf16 hi/lo split helpers ----------------
__device__ __forceinline__ unsigned short f2bf(float x) {
    unsigned u = __float_as_uint(x);
    u += 0x7fffu + ((u >> 16) & 1u);
    return (unsigned short)(u >> 16);
}
__device__ __forceinline__ float bf2f(unsigned short h) {
    return __uint_as_float(((unsigned)h) << 16);
}

// ---------------- fused prep: embsplit + rowsum + splitT(Wd1) + splitT(Wd2) + flag reset --
__global__ __launch_bounds__(256) void prep_kernel(
    const float* __restrict__ emb, float* __restrict__ e2,
    short* __restrict__ eh, short* __restrict__ el,
    const float* __restrict__ z, float* __restrict__ az2,
    const float* __restrict__ Wd1, short* __restrict__ Wd1hT, short* __restrict__ Wd1lT,
    const float* __restrict__ Wd2, short* __restrict__ Wd2hT, short* __restrict__ Wd2lT,
    int* __restrict__ flagcnt)
{
    int blk = blockIdx.x;
    int tid = threadIdx.x;
    if (blk == 0 && tid == 0) *flagcnt = 0;
    if (blk < 8) {
        // ---- embsplit: e2[k] np-exact + emb hi/lo split ----
        int k = blk * 256 + tid;
        const float* p = emb + (long)k * D_N;
        float r[8];
#pragma unroll
        for (int i = 0; i < 128; i += 8) {
            float4 a = *(const float4*)&p[i];
            float4 b = *(const float4*)&p[i + 4];
            float v[8] = {a.x, a.y, a.z, a.w, b.x, b.y, b.z, b.w};
            if (i == 0) {
#pragma unroll
                for (int j = 0; j < 8; j++) r[j] = sqf(v[j]);
            } else {
#pragma unroll
                for (int j = 0; j < 8; j++) r[j] = r[j] + sqf(v[j]);  // PROTECTED order
            }
            short4 h0, h1, l0, l1;
            h0.x = (short)f2bf(v[0]); l0.x = (short)f2bf(v[0] - bf2f(h0.x));
            h0.y = (short)f2bf(v[1]); l0.y = (short)f2bf(v[1] - bf2f(h0.y));
            h0.z = (short)f2bf(v[2]); l0.z = (short)f2bf(v[2] - bf2f(h0.z));
            h0.w = (short)f2bf(v[3]); l0.w = (short)f2bf(v[3] - bf2f(h0.w));
            h1.x = (short)f2bf(v[4]); l1.x = (short)f2bf(v[4] - bf2f(h1.x));
            h1.y = (short)f2bf(v[5]); l1.y = (short)f2bf(v[5] - bf2f(h1.y));
            h1.z = (short)f2bf(v[6]); l1.z = (short)f2bf(v[6] - bf2f(h1.z));
            h1.w = (short)f2bf(v[7]); l1.w = (short)f2bf(v[7] - bf2f(h1.w));
            *(short4*)&eh[(long)k * D_N + i] = h0;
            *(short4*)&eh[(long)k * D_N + i + 4] = h1;
            *(short4*)&el[(long)k * D_N + i] = l0;
            *(short4*)&el[(long)k * D_N + i + 4] = l1;
        }
        e2[k] = ((r[0] + r[1]) + (r[2] + r[3])) + ((r[4] + r[5]) + (r[6] + r[7]));
    } else if (blk < 136) {
        // ---- rowsum: az2[r] np-exact ----
        int r = (blk - 8) * 256 + tid;
        az2[r] = np_sumsq_128(z + (long)r * D_N);
    } else if (blk < 264) {
        // ---- splitT Wd1: [k][n] -> [n][128] ----
        int i = (blk - 136) * 256 + tid;
        int k = i >> 8;
        int n = i & 255;
        float v = Wd1[i];
        unsigned short h = f2bf(v);
        Wd1hT[(long)n * D_N + k] = (short)h;
        Wd1lT[(long)n * D_N + k] = (short)f2bf(v - bf2f(h));
    } else {
        // ---- splitT Wd2: [k][n] -> [n][256] ----
        int i = (blk - 264) * 256 + tid;
        int k = i >> 8;
        int n = i & 255;
        float v = Wd2[i];
        unsigned short h = f2bf(v);
        Wd2hT[(long)n * H_N + k] = (short)h;
        Wd2lT[(long)n * H_N + k] = (short)f2bf(v - bf2f(h));
    }
}

// ---------------- encoder layer 1 (protected fp32 fmaf chain) ----------------
__global__ __launch_bounds__(256) void enc1_kernel(const float* __restrict__ action,
    const float* __restrict__ W, const float* __restrict__ bias, float* __restrict__ out)
{
    __shared__ float as[8][6];
    int tid = threadIdx.x;
    int row0 = blockIdx.x * 8;
    if (tid < 48) as[tid / 6][tid % 6] = action[(long)(row0 + tid / 6) * A_N + tid % 6];
    __syncthreads();
    int col = tid;
    float w[6];
#pragma unroll
    for (int k = 0; k < 6; k++) w[k] = W[k * H_N + col];
    float bv = bias[col];
#pragma unroll
    for (int r = 0; r < 8; r++) {
        float acc = bv;
#pragma unroll
        for (int k = 0; k < 6; k++) acc = fmaf(as[r][k], w[k], acc);
        out[(long)(row0 + r) * H_N + col] = fmaxf(acc, 0.0f);
    }
}

// ---------------- encoder fp32 GEMM: 512 threads, 128x128 tile, 8x4/thread ----------------
// (z bits PROTECTED: one fmaf per k per C element, k ascending — k0 outer + kk inner;
// one thread per C element.)
// R20 post-mortem: 256-thr shapes plateau ~70us. 512-thr 128x128 halves barrier+staging
// cost per output at the same 16 waves/CU (enc2). Col ownership {2tx,2tx+1,64+2tx,64+2tx+1}
// -> B-reads are two b64 at 2-way aliasing (free, m136). XCD remap retained (bijective).
template<int RELU, int SPLITZ>
__global__ __launch_bounds__(512, 2) void gemm_rt(const float* __restrict__ Amat,
    const float* __restrict__ W, const float* __restrict__ bias,
    float* __restrict__ Omat, int Kdim, int N,
    short* __restrict__ OhS, short* __restrict__ OlS)
{
    __shared__ float As[32][132];   // k-major: As[k][row]
    __shared__ float Bs[32][132];   // k-major: Bs[k][col], 128 cols + pad
    int tid = threadIdx.x;          // 0..511
    int tx = tid & 31, ty = tid >> 5;   // tx: 32 col-groups, ty: 16 row-groups
    int bid = blockIdx.y * gridDim.x + blockIdx.x;
    int by = bid % gridDim.y;       // bijective remap: same-panel blocks land on one XCD
    int bx = bid / gridDim.y;
    int row0 = by * 128;
    int col0 = bx * 128;
    float acc[8][4];
#pragma unroll
    for (int i = 0; i < 8; i++)
#pragma unroll
        for (int j = 0; j < 4; j++) acc[i][j] = 0.0f;

    for (int k0 = 0; k0 < Kdim; k0 += 32) {
        for (int f = tid; f < 1024; f += 512) {
            int r = f >> 3, k4 = (f & 7) * 4;
            float4 v = *(const float4*)&Amat[(long)(row0 + r) * Kdim + k0 + k4];
            As[k4 + 0][r] = v.x; As[k4 + 1][r] = v.y; As[k4 + 2][r] = v.z; As[k4 + 3][r] = v.w;
        }
        for (int f = tid; f < 1024; f += 512) {
            int kr = f >> 5, c4 = (f & 31) * 4;
            *(float4*)&Bs[kr][c4] = *(const float4*)&W[(long)(k0 + kr) * N + col0 + c4];
        }
        __syncthreads();
#pragma unroll
        for (int kk = 0; kk < 32; kk++) {
            float4 a0 = *(const float4*)&As[kk][ty * 8];
            float4 a1 = *(const float4*)&As[kk][ty * 8 + 4];
            float2 b0 = *(const float2*)&Bs[kk][tx * 2];
            float2 b1 = *(const float2*)&Bs[kk][64 + tx * 2];
            float av[8] = {a0.x, a0.y, a0.z, a0.w, a1.x, a1.y, a1.z, a1.w};
            float bv[4] = {b0.x, b0.y, b1.x, b1.y};
#pragma unroll
            for (int i = 0; i < 8; i++)
#pragma unroll
                for (int j = 0; j < 4; j++)
                    acc[i][j] = fmaf(av[i], bv[j], acc[i][j]);
        }
        __syncthreads();
    }
#pragma unroll
    for (int i = 0; i < 8; i++) {
        long r = row0 + ty * 8 + i;
        int c0 = col0 + tx * 2;
        int c1 = col0 + 64 + tx * 2;
        float2 o0, o1;
        o0.x = acc[i][0] + bias[c0 + 0];
        o0.y = acc[i][1] + bias[c0 + 1];
        o1.x = acc[i][2] + bias[c1 + 0];
        o1.y = acc[i][3] + bias[c1 + 1];
        if (RELU) {
            o0.x = fmaxf(o0.x, 0.0f); o0.y = fmaxf(o0.y, 0.0f);
            o1.x = fmaxf(o1.x, 0.0f); o1.y = fmaxf(o1.y, 0.0f);
        }
        *(float2*)&Omat[r * N + c0] = o0;
        *(float2*)&Omat[r * N + c1] = o1;
        if (SPLITZ) {   // fused z hi/lo split (identical bits to the old split_kernel)
            short2 h0, l0, h1, l1;
            h0.x = (short)f2bf(o0.x); l0.x = (short)f2bf(o0.x - bf2f(h0.x));
            h0.y = (short)f2bf(o0.y); l0.y = (short)f2bf(o0.y - bf2f(h0.y));
            h1.x = (short)f2bf(o1.x); l1.x = (short)f2bf(o1.x - bf2f(h1.x));
            h1.y = (short)f2bf(o1.y); l1.y = (short)f2bf(o1.y - bf2f(h1.y));
            *(short2*)&OhS[r * N + c0] = h0;
            *(short2*)&OhS[r * N + c1] = h1;
            *(short2*)&OlS[r * N + c0] = l0;
            *(short2*)&OlS[r * N + c1] = l1;
        }
    }
}

// ---------------- VQ candidates: 32-code tiles, 4 independent MFMA chains (R17-validated) --
__global__ __launch_bounds__(256, 2) void vq_mfma(const short* __restrict__ zh,
    const short* __restrict__ zl, const short* __restrict__ eh, const short* __restrict__ el,
    const float* __restrict__ az2, const float* __restrict__ e2,
    float4* __restrict__ twq /* [B][CB_N] = (v1, i1-bits, v2, 0) */)
{
    __shared__ short ehs[2][32 * 136];
    __shared__ short els[2][32 * 136];
    int tid = threadIdx.x;
    int wave = tid >> 6, lane = tid & 63;
    int lo = lane & 15, hi = lane >> 4;
    int row0 = blockIdx.y * 64 + wave * 16;
    int code0 = blockIdx.x * CPC;

    bf16x8 ahf[4], alf[4];
#pragma unroll
    for (int ks = 0; ks < 4; ks++) {
        long o = (long)(row0 + lo) * D_N + ks * 32 + hi * 8;
        ahf[ks] = *(const bf16x8*)&zh[o];
        alf[ks] = *(const bf16x8*)&zl[o];
    }
    float az_r[4];
#pragma unroll
    for (int r = 0; r < 4; r++) az_r[r] = az2[row0 + hi * 4 + r];

    float v1[4], v2[4];
    int   i1[4];
#pragma unroll
    for (int r = 0; r < 4; r++) { v1[r] = v2[r] = 1e30f; i1[r] = 0; }

    {   // stage tile 0 into buf 0 (32 codes x 128 d, 2 units/thread/array)
#pragma unroll
        for (int u = 0; u < 2; u++) {
            int f = tid + u * 256;
            int scode = f >> 4, sq = f & 15;
            long g = (long)(code0 + scode) * D_N + sq * 8;
            *(bf16x8*)&ehs[0][scode * 136 + sq * 8] = *(const bf16x8*)&eh[g];
            *(bf16x8*)&els[0][scode * 136 + sq * 8] = *(const bf16x8*)&el[g];
        }
    }
    __syncthreads();

#pragma unroll 1
    for (int t = 0; t < CPC / 32; t++) {
        int buf = t & 1;
        bf16x8 nh[2], nl[2];
        bool more = (t + 1 < CPC / 32);
        if (more) {   // issue next-tile loads early (latency hides under MFMA)
#pragma unroll
            for (int u = 0; u < 2; u++) {
                int f = tid + u * 256;
                int scode = f >> 4, sq = f & 15;
                long g = (long)(code0 + (t + 1) * 32 + scode) * D_N + sq * 8;
                nh[u] = *(const bf16x8*)&eh[g];
                nl[u] = *(const bf16x8*)&el[g];
            }
        }
        int codeA = code0 + t * 32 + lo;          // cb=0 column
        int codeB = codeA + 16;                   // cb=1 column
        float e2A = e2[codeA];
        float e2B = e2[codeB];
        f32x4 a1A = {0.f, 0.f, 0.f, 0.f}, a2A = {0.f, 0.f, 0.f, 0.f};
        f32x4 a1B = {0.f, 0.f, 0.f, 0.f}, a2B = {0.f, 0.f, 0.f, 0.f};
#pragma unroll
        for (int ks = 0; ks < 4; ks++) {
            bf16x8 bhA = *(const bf16x8*)&ehs[buf][lo * 136 + ks * 32 + hi * 8];
            bf16x8 blA = *(const bf16x8*)&els[buf][lo * 136 + ks * 32 + hi * 8];
            bf16x8 bhB = *(const bf16x8*)&ehs[buf][(16 + lo) * 136 + ks * 32 + hi * 8];
            bf16x8 blB = *(const bf16x8*)&els[buf][(16 + lo) * 136 + ks * 32 + hi * 8];
            a1A = __builtin_amdgcn_mfma_f32_16x16x32_bf16(ahf[ks], bhA, a1A, 0, 0, 0);
            a1B = __builtin_amdgcn_mfma_f32_16x16x32_bf16(ahf[ks], bhB, a1B, 0, 0, 0);
            a2A = __builtin_amdgcn_mfma_f32_16x16x32_bf16(ahf[ks], blA, a2A, 0, 0, 0);
            a2B = __builtin_amdgcn_mfma_f32_16x16x32_bf16(ahf[ks], blB, a2B, 0, 0, 0);
            a1A = __builtin_amdgcn_mfma_f32_16x16x32_bf16(alf[ks], bhA, a1A, 0, 0, 0);
            a1B = __builtin_amdgcn_mfma_f32_16x16x32_bf16(alf[ks], bhB, a1B, 0, 0, 0);
        }
#pragma unroll
        for (int r = 0; r < 4; r++) {          // cb=0 first: in-lane codes ascend
            float dot = a1A[r] + a2A[r];
            float s = (az_r[r] + e2A) - 2.0f * dot;
            bool lt = s < v1[r];               // strict: first-min on ties
            i1[r] = lt ? codeA : i1[r];
            v2[r] = fminf(v2[r], fmaxf(v1[r], s));
            v1[r] = fminf(v1[r], s);
        }
#pragma unroll
        for (int r = 0; r < 4; r++) {
            float dot = a1B[r] + a2B[r];
            float s = (az_r[r] + e2B) - 2.0f * dot;
            bool lt = s < v1[r];
            i1[r] = lt ? codeB : i1[r];
            v2[r] = fminf(v2[r], fmaxf(v1[r], s));
            v1[r] = fminf(v1[r], s);
        }
        if (more) {   // write-late into alternate buffer
#pragma unroll
            for (int u = 0; u < 2; u++) {
                int f = tid + u * 256;
                int scode = f >> 4, sq = f & 15;
                *(bf16x8*)&ehs[buf ^ 1][scode * 136 + sq * 8] = nh[u];
                *(bf16x8*)&els[buf ^ 1][scode * 136 + sq * 8] = nl[u];
            }
        }
        __syncthreads();
    }

    // 16-lane butterfly: lex-min (v1,i1), v2 = min(v2a, v2b, max(v1a, v1b))
#pragma unroll
    for (int m = 1; m < 16; m <<= 1) {
#pragma unroll
        for (int r = 0; r < 4; r++) {
            float ov1 = __shfl_xor(v1[r], m, 16);
            int   oi1 = __shfl_xor(i1[r], m, 16);
            float ov2 = __shfl_xor(v2[r], m, 16);
            v2[r] = fminf(fminf(v2[r], ov2), fmaxf(v1[r], ov1));
            bool bl = (ov1 < v1[r]) || (ov1 == v1[r] && oi1 < i1[r]);
            v1[r] = bl ? ov1 : v1[r];
            i1[r] = bl ? oi1 : i1[r];
        }
    }
    if (lo == 0) {
#pragma unroll
        for (int r = 0; r < 4; r++) {
            twq[(long)(row0 + hi * 4 + r) * CB_N + blockIdx.x] =
                make_float4(v1[r], __int_as_float(i1[r]), v2[r], 0.0f);
        }
    }
}

// ---------------- pick: exact refine of the CB_N candidates + cert + fused vq-loss -------
__global__ __launch_bounds__(256) void vq_pick(const float4* __restrict__ twq,
    const float* __restrict__ z, const float* __restrict__ emb,
    const float* __restrict__ az2, const float* __restrict__ e2,
    int* __restrict__ idxI, float* __restrict__ outIdx,
    int* __restrict__ flaglist, int* __restrict__ flagcnt,
    unsigned long long* __restrict__ key, float* __restrict__ vqp)
{
    __shared__ float red[256];
    int tid = threadIdx.x;
    long g = (long)blockIdx.x * 256 + tid;
    int r = (int)(g >> 1), which = (int)(g & 1);
    float4 t = twq[(long)r * CB_N + which];
    int c = __float_as_int(t.y);
    const float* zr = z + (long)r * D_N;
    const float* ec = emb + (long)c * D_N;
    float C = 0.0f;
    for (int d = 0; d < D_N; d++) C = fmaf(zr[d], ec[d], C);   // PROTECTED chain
    float d2 = (az2[r] + e2[c]) - 2.0f * C;
    float od2 = __shfl_xor(d2, 1, 64);
    int   oc  = __shfl_xor(c, 1, 64);
    float ov2 = __shfl_xor(t.z, 1, 64);
    float bd = d2; int bi = c;
    if (od2 < bd || (od2 == bd && oc < bi)) { bd = od2; bi = oc; }
    float v2min = fminf(t.z, ov2);
    float contrib = 0.0f;
    if (which == 0) {
        idxI[r] = bi;
        outIdx[r] = (float)bi;
        key[r] = 0xFFFFFFFFFFFFFFFFull;
        if (v2min <= bd + MU_CERT) {
            int s = atomicAdd(flagcnt, 1);
            flaglist[s] = r;
        }
        contrib = bd;   // exact ||z-q||^2 for this row (flagged-row error negligible)
    }
    red[tid] = contrib;
    __syncthreads();
    for (int o = 128; o > 0; o >>= 1) { if (tid < o) red[tid] += red[tid + o]; __syncthreads(); }
    if (tid == 0) vqp[blockIdx.x] = red[0];
}

// ---------------- exact scan for flagged rows: one BLOCK per (row, 256-code chunk) --------
__global__ __launch_bounds__(256) void vq_fallback(const float* __restrict__ z,
    const float* __restrict__ emb, const float* __restrict__ az2, const float* __restrict__ e2,
    const int* __restrict__ flaglist, const int* __restrict__ flagcnt,
    unsigned long long* __restrict__ key)
{
    __shared__ float zs[128];
    __shared__ unsigned long long rk[256];
    int n = *flagcnt;
    int tid = threadIdx.x;
    long total = (long)n * 8;
    for (long w = blockIdx.x; w < total; w += gridDim.x) {
        __syncthreads();
        int r = flaglist[w >> 3];
        int chunk = (int)(w & 7);
        if (tid < 32) *(float4*)&zs[tid * 4] = *(const float4*)&z[(long)r * D_N + tid * 4];
        __syncthreads();
        int code = chunk * 256 + tid;
        const float4* er = (const float4*)&emb[(long)code * D_N];
        float C = 0.0f;
#pragma unroll
        for (int q = 0; q < 32; q++) {         // EXACT ascending-d chain (PROTECTED)
            float4 e4 = er[q];
            float4 z4 = *(const float4*)&zs[q * 4];
            C = fmaf(z4.x, e4.x, C);
            C = fmaf(z4.y, e4.y, C);
            C = fmaf(z4.z, e4.z, C);
            C = fmaf(z4.w, e4.w, C);
        }
        float d2 = (az2[r] + e2[code]) - 2.0f * C;
        unsigned ub = __float_as_uint(d2);
        ub ^= (ub >> 31) ? 0xFFFFFFFFu : 0x80000000u;
        rk[tid] = ((unsigned long long)ub << 32) | (unsigned)code;
        __syncthreads();
        for (int o = 128; o > 0; o >>= 1) {
            if (tid < o) rk[tid] = rk[tid] < rk[tid + o] ? rk[tid] : rk[tid + o];
            __syncthreads();
        }
        if (tid == 0) atomicMin(&key[r], rk[0]);
    }
}

__global__ __launch_bounds__(256) void vq_finalize(const int* __restrict__ flaglist,
    const int* __restrict__ flagcnt, const unsigned long long* __restrict__ key,
    int* __restrict__ idxI, float* __restrict__ outIdx)
{
    int i = blockIdx.x * 256 + threadIdx.x;
    if (i < *flagcnt) {
        int r = flaglist[i];
        int c = (int)(key[r] & 0xFFFFFFFFull);
        idxI[r] = c;
        outIdx[r] = (float)c;
    }
}

// ---------------- decoder GEMM via bf16-split MFMA (R13-validated) ----------
template<int KD, int GATHER, int SPLITOUT>
__global__ __launch_bounds__(256, 2) void gemm_mfma(
    const short* __restrict__ Ah, const short* __restrict__ Al,
    const short* __restrict__ BhT, const short* __restrict__ BlT,   // [n][KD]
    const float* __restrict__ bias, const int* __restrict__ gidx,
    float* __restrict__ OutF, short* __restrict__ OutH, short* __restrict__ OutL)
{
    constexpr int KS = KD / 32;
    constexpr int LDB = KD + 8;
    __shared__ short Bh[64 * LDB];
    __shared__ short Bl[64 * LDB];
    int tid = threadIdx.x;
    int wave = tid >> 6, lane = tid & 63;
    int lo = lane & 15, hi = lane >> 4;
    int row0 = blockIdx.y * 64 + wave * 16;
    int c0 = blockIdx.x * 64;

    for (int f = tid; f < 64 * (KD / 8); f += 256) {
        int c = f / (KD / 8), q = f % (KD / 8);
        *(bf16x8*)&Bh[c * LDB + q * 8] = *(const bf16x8*)&BhT[(long)(c0 + c) * KD + q * 8];
        *(bf16x8*)&Bl[c * LDB + q * 8] = *(const bf16x8*)&BlT[(long)(c0 + c) * KD + q * 8];
    }
    int arow = row0 + lo;
    long abase = (GATHER ? (long)gidx[arow] : (long)arow) * KD;
    bf16x8 ah[KS], al[KS];
#pragma unroll
    for (int ks = 0; ks < KS; ks++) {
        ah[ks] = *(const bf16x8*)&Ah[abase + ks * 32 + hi * 8];
        al[ks] = *(const bf16x8*)&Al[abase + ks * 32 + hi * 8];
    }
    __syncthreads();

    f32x4 a1[4], a2[4];
#pragma unroll
    for (int g = 0; g < 4; g++) {
        a1[g] = (f32x4){0.f, 0.f, 0.f, 0.f};
        a2[g] = (f32x4){0.f, 0.f, 0.f, 0.f};
    }
#pragma unroll
    for (int g = 0; g < 4; g++) {
        int cb = (g * 16 + lo) * LDB;
#pragma unroll
        for (int ks = 0; ks < KS; ks++) {
            bf16x8 bh = *(const bf16x8*)&Bh[cb + ks * 32 + hi * 8];
            bf16x8 bl = *(const bf16x8*)&Bl[cb + ks * 32 + hi * 8];
            a1[g] = __builtin_amdgcn_mfma_f32_16x16x32_bf16(ah[ks], bh, a1[g], 0, 0, 0);
            a2[g] = __builtin_amdgcn_mfma_f32_16x16x32_bf16(ah[ks], bl, a2[g], 0, 0, 0);
            a1[g] = __builtin_amdgcn_mfma_f32_16x16x32_bf16(al[ks], bh, a1[g], 0, 0, 0);
        }
    }
#pragma unroll
    for (int g = 0; g < 4; g++) {
        int col = c0 + g * 16 + lo;
        float bv = bias[col];
#pragma unroll
        for (int r = 0; r < 4; r++) {
            long row = row0 + hi * 4 + r;
            float v = fmaxf((a1[g][r] + a2[g][r]) + bv, 0.0f);
            if (SPLITOUT) {
                unsigned short h = f2bf(v);
                OutH[row * 256 + col] = (short)h;
                OutL[row * 256 + col] = (short)f2bf(v - bf2f(h));
            } else {
                OutF[row * 256 + col] = v;
            }
        }
    }
}

// ---------------- head: recons = tanh(d2 @ Wh + bh), partial recon loss ----------------
__global__ __launch_bounds__(256) void head_kernel(const float* __restrict__ dbuf,
    const float* __restrict__ Wh, const float* __restrict__ bh,
    const float* __restrict__ action, float* __restrict__ outRec, float* __restrict__ part)
{
    __shared__ float WhS[H_N * A_N];
    __shared__ float red[256];
    int tid = threadIdx.x;
    for (int i = tid; i < H_N * A_N; i += 256) WhS[i] = Wh[i];
    __syncthreads();
    long t = (long)blockIdx.x * 256 + tid;
    int row = (int)(t / 6), col = (int)(t % 6);
    const float* dr = dbuf + (long)row * H_N;
    float acc = bh[col];
    for (int k = 0; k < H_N; k++) acc = fmaf(dr[k], WhS[k * 6 + col], acc);
    float rec = tanhf(acc);
    outRec[t] = rec;
    float diff = rec - action[t];
    red[tid] = diff * diff;
    __syncthreads();
    for (int o = 128; o > 0; o >>= 1) { if (tid < o) red[tid] += red[tid + o]; __syncthreads(); }
    if (tid == 0) part[blockIdx.x] = red[0];
}

// ---------------- finalize scalars ----------------
__global__ void final_kernel(const float* __restrict__ vqp, const float* __restrict__ recp,
                             float* __restrict__ out)
{
    if (threadIdx.x == 0 && blockIdx.x == 0) {
        double vs = 0.0;
        for (int i = 0; i < 256; i++) vs += (double)vqp[i];
        double rs = 0.0;
        for (int i = 0; i < 768; i++) rs += (double)recp[i];
        double m = vs / 4194304.0;           // B*D
        double vql = 1.25 * m;               // beta*commit + embed (forward-equal)
        double rl = rs / 196608.0;           // B*A
        out[0] = (float)(rl + vql);
        out[1] = (float)vql;
        out[2] = (float)rl;
    }
}

extern "C" void kernel_launch(void* const* d_in, const int* in_sizes, int n_in,
                              void* d_out, int out_size, void* d_ws, size_t ws_size,
                              hipStream_t stream)
{
    (void)in_sizes; (void)n_in; (void)out_size; (void)ws_size;
    const float* action = (const float*)d_in[0];
    const float* We1 = (const float*)d_in[1];
    const float* be1 = (const float*)d_in[2];
    const float* We2 = (const float*)d_in[3];
    const float* be2 = (const float*)d_in[4];
    const float* We3 = (const float*)d_in[5];
    const float* be3 = (const float*)d_in[6];
    const float* emb = (const float*)d_in[7];
    const float* Wd1 = (const float*)d_in[8];
    const float* bd1 = (const float*)d_in[9];
    const float* Wd2 = (const float*)d_in[10];
    const float* bd2 = (const float*)d_in[11];
    const float* Wh  = (const float*)d_in[12];
    const float* bh  = (const float*)d_in[13];
    float* out = (float*)d_out;

    // workspace layout (~85 MB):
    //   h1 region (B*H f32): enc-h1 -> zh/zl/eh/el (VQ) -> dec2 f32 output
    //   h2 region (B*H f32): enc-h2 -> twq/flaglist/flagcnt -> h1h/h1l (dec)
    //   z   (B*D f32)
    //   tail: az2(B) e2(K) idxI(B) vqp(256) recp(768) key(B u64) Wd splits
    float* h1 = (float*)d_ws;
    float* h2 = h1 + (long)B_N * H_N;
    float* z  = h2 + (long)B_N * H_N;
    float* az2 = z + (long)B_N * D_N;
    float* e2  = az2 + B_N;
    int*   idxI = (int*)(e2 + K_N);
    float* vqp  = (float*)(idxI + B_N);
    float* recp = vqp + 512;
    unsigned long long* key = (unsigned long long*)(recp + 768);
    short* Wd1hT = (short*)(key + B_N);               // 128*256
    short* Wd1lT = Wd1hT + D_N * H_N;
    short* Wd2hT = Wd1lT + D_N * H_N;                 // 256*256
    short* Wd2lT = Wd2hT + H_N * H_N;

    short* zh = (short*)h1;                 // 8.4 MB (written by gemm3 epilogue)
    short* zl = zh + (long)B_N * D_N;       // 8.4 MB
    short* eh = zl + (long)B_N * D_N;       // 0.5 MB (written by prep, after gemm2)
    short* el = eh + (long)K_N * D_N;       // 0.5 MB
    float4* twq = (float4*)h2;              // B*CB_N float4 = 1 MB
    int* flaglist = (int*)(twq + (long)B_N * CB_N);
    int* flagcnt  = flaglist + B_N;
    short* h1h = (short*)h2;                // dec h1 split (written AFTER vq_finalize)
    short* h1l = h1h + (long)B_N * H_N;
    float* d2f = h1;                        // dec2 f32 out (written AFTER dec1)

    // encoder (protected fp32 chains; gemm3 also emits zh/zl)
    enc1_kernel<<<B_N / 8, 256, 0, stream>>>(action, We1, be1, h1);
    gemm_rt<1, 0><<<dim3(2, B_N / 128), 512, 0, stream>>>(h1, We2, be2, h2, H_N, H_N,
                                                          nullptr, nullptr);
    gemm_rt<0, 1><<<dim3(1, B_N / 128), 512, 0, stream>>>(h2, We3, be3, z, H_N, D_N,
                                                          zh, zl);

    // fused prep: embsplit + rowsum + splitT(Wd1) + splitT(Wd2) + flagcnt reset (1 launch)
    prep_kernel<<<520, 256, 0, stream>>>(emb, e2, eh, el, z, az2,
                                         Wd1, Wd1hT, Wd1lT, Wd2, Wd2hT, Wd2lT, flagcnt);

    // VQ: MFMA candidates -> exact refine + cert + fused loss -> chunked exact scan
    vq_mfma<<<dim3(CB_N, B_N / 64), 256, 0, stream>>>(zh, zl, eh, el, az2, e2, twq);
    vq_pick<<<(B_N * 2) / 256, 256, 0, stream>>>(twq, z, emb, az2, e2, idxI, out + 3,
                                                 flaglist, flagcnt, key, vqp);
    vq_fallback<<<4096, 256, 0, stream>>>(z, emb, az2, e2, flaglist, flagcnt, key);
    vq_finalize<<<B_N / 256, 256, 0, stream>>>(flaglist, flagcnt, key, idxI, out + 3);

    // decoder via MFMA (R13-validated)
    gemm_mfma<D_N, 1, 1><<<dim3(H_N / 64, B_N / 64), 256, 0, stream>>>(
        eh, el, Wd1hT, Wd1lT, bd1, idxI, nullptr, h1h, h1l);
    gemm_mfma<H_N, 0, 0><<<dim3(H_N / 64, B_N / 64), 256, 0, stream>>>(
        h1h, h1l, Wd2hT, Wd2lT, bd2, nullptr, d2f, nullptr, nullptr);

    // head + losses
    head_kernel<<<(B_N * A_N) / 256, 256, 0, stream>>>(d2f, Wh, bh, action, out + 3 + B_N, recp);
    final_kernel<<<1, 64, 0, stream>>>(vqp, recp, out);
}

// Round 22
// 295.357 us; speedup vs baseline: 1.0341x; 1.0341x over previous
//
#include <hip/hip_runtime.h>
#include <math.h>

#define B_N 32768
#define A_N 6
#define H_N 256
#define D_N 128
#define K_N 2048
#define MU_CERT 2e-8f   // >= 4x the bf16-split approx error bound (~5e-9)
#define CB_N 2          // code-dimension split of vq_mfma
#define CPC (K_N / CB_N)

typedef __attribute__((ext_vector_type(8))) short bf16x8;
typedef __attribute__((ext_vector_type(4))) float f32x4;

// Block compiler from contracting a*a into subsequent adds (np computes z*z array, then sums it)
__device__ __forceinline__ float sqf(float v) {
    float s = v * v;
    asm volatile("" : "+v"(s));
    return s;
}

// numpy pairwise_sum for n=128 contiguous fp32: 8 accumulators stride-8 + fixed 3-level tree.
// Bitwise replication of np.sum(x*x, axis=-1). PROTECTED SEMANTICS: do not alter the add order.
__device__ __forceinline__ float np_sumsq_128(const float* __restrict__ p)
{
    float r[8];
#pragma unroll
    for (int j = 0; j < 8; j++) r[j] = sqf(p[j]);
#pragma unroll
    for (int i = 8; i < 128; i += 8) {
#pragma unroll
        for (int j = 0; j < 8; j++) r[j] = r[j] + sqf(p[i + j]);
    }
    return ((r[0] + r[1]) + (r[2] + r[3])) + ((r[4] + r[5]) + (r[6] + r[7]));
}

// ---------------- bf16 hi/lo split helpers ----------------
__device__ __forceinline__ unsigned short f2bf(float x) {
    unsigned u = __float_as_uint(x);
    u += 0x7fffu + ((u >> 16) & 1u);
    return (unsigned short)(u >> 16);
}
__device__ __forceinline__ float bf2f(unsigned short h) {
    return __uint_as_float(((unsigned)h) << 16);
}

// ---------------- fused prep: embsplit + rowsum + splitT(Wd1) + splitT(Wd2) + flag reset --
__global__ __launch_bounds__(256) void prep_kernel(
    const float* __restrict__ emb, float* __restrict__ e2,
    short* __restrict__ eh, short* __restrict__ el,
    const float* __restrict__ z, float* __restrict__ az2,
    const float* __restrict__ Wd1, short* __restrict__ Wd1hT, short* __restrict__ Wd1lT,
    const float* __restrict__ Wd2, short* __restrict__ Wd2hT, short* __restrict__ Wd2lT,
    int* __restrict__ flagcnt)
{
    int blk = blockIdx.x;
    int tid = threadIdx.x;
    if (blk == 0 && tid == 0) *flagcnt = 0;
    if (blk < 8) {
        // ---- embsplit: e2[k] np-exact + emb hi/lo split ----
        int k = blk * 256 + tid;
        const float* p = emb + (long)k * D_N;
        float r[8];
#pragma unroll
        for (int i = 0; i < 128; i += 8) {
            float4 a = *(const float4*)&p[i];
            float4 b = *(const float4*)&p[i + 4];
            float v[8] = {a.x, a.y, a.z, a.w, b.x, b.y, b.z, b.w};
            if (i == 0) {
#pragma unroll
                for (int j = 0; j < 8; j++) r[j] = sqf(v[j]);
            } else {
#pragma unroll
                for (int j = 0; j < 8; j++) r[j] = r[j] + sqf(v[j]);  // PROTECTED order
            }
            short4 h0, h1, l0, l1;
            h0.x = (short)f2bf(v[0]); l0.x = (short)f2bf(v[0] - bf2f(h0.x));
            h0.y = (short)f2bf(v[1]); l0.y = (short)f2bf(v[1] - bf2f(h0.y));
            h0.z = (short)f2bf(v[2]); l0.z = (short)f2bf(v[2] - bf2f(h0.z));
            h0.w = (short)f2bf(v[3]); l0.w = (short)f2bf(v[3] - bf2f(h0.w));
            h1.x = (short)f2bf(v[4]); l1.x = (short)f2bf(v[4] - bf2f(h1.x));
            h1.y = (short)f2bf(v[5]); l1.y = (short)f2bf(v[5] - bf2f(h1.y));
            h1.z = (short)f2bf(v[6]); l1.z = (short)f2bf(v[6] - bf2f(h1.z));
            h1.w = (short)f2bf(v[7]); l1.w = (short)f2bf(v[7] - bf2f(h1.w));
            *(short4*)&eh[(long)k * D_N + i] = h0;
            *(short4*)&eh[(long)k * D_N + i + 4] = h1;
            *(short4*)&el[(long)k * D_N + i] = l0;
            *(short4*)&el[(long)k * D_N + i + 4] = l1;
        }
        e2[k] = ((r[0] + r[1]) + (r[2] + r[3])) + ((r[4] + r[5]) + (r[6] + r[7]));
    } else if (blk < 136) {
        // ---- rowsum: az2[r] np-exact ----
        int r = (blk - 8) * 256 + tid;
        az2[r] = np_sumsq_128(z + (long)r * D_N);
    } else if (blk < 264) {
        // ---- splitT Wd1: [k][n] -> [n][128] ----
        int i = (blk - 136) * 256 + tid;
        int k = i >> 8;
        int n = i & 255;
        float v = Wd1[i];
        unsigned short h = f2bf(v);
        Wd1hT[(long)n * D_N + k] = (short)h;
        Wd1lT[(long)n * D_N + k] = (short)f2bf(v - bf2f(h));
    } else {
        // ---- splitT Wd2: [k][n] -> [n][256] ----
        int i = (blk - 264) * 256 + tid;
        int k = i >> 8;
        int n = i & 255;
        float v = Wd2[i];
        unsigned short h = f2bf(v);
        Wd2hT[(long)n * H_N + k] = (short)h;
        Wd2lT[(long)n * H_N + k] = (short)f2bf(v - bf2f(h));
    }
}

// ---------------- enc1+enc2 fused GEMM: 512 threads, 128x128 tile, 8x4/thread ------------
// A-tile (h1) computed on the fly from action/We1/be1 with the EXACT enc1 fmaf chain:
// acc = be1[k]; 6x fmaf(act[r][a], We1[a][k]) ascending a; relu. Same expression as the
// old enc1 kernel -> identical bits (PROTECTED). Main loop unchanged: one fmaf per k per
// C element, k ascending. Eliminates the enc1 launch + h1 HBM round-trip.
__global__ __launch_bounds__(512, 2) void gemm_enc2(const float* __restrict__ action,
    const float* __restrict__ We1, const float* __restrict__ be1,
    const float* __restrict__ W, const float* __restrict__ bias,
    float* __restrict__ Omat)
{
    __shared__ float As[32][132];   // k-major: As[k][row] (holds computed h1)
    __shared__ float Bs[32][132];   // k-major: Bs[k][col]
    __shared__ float acts[128][8];  // action rows (6 used, pad to 8)
    __shared__ float we1s[6][256];
    __shared__ float be1s[256];
    int tid = threadIdx.x;          // 0..511
    int tx = tid & 31, ty = tid >> 5;
    int bid = blockIdx.y * gridDim.x + blockIdx.x;
    int by = bid % gridDim.y;       // bijective remap (XCD locality; harmless here)
    int bx = bid / gridDim.y;
    int row0 = by * 128;
    int col0 = bx * 128;

    // stage action rows + We1 + be1 once
    for (int f = tid; f < 128 * A_N; f += 512)
        acts[f / A_N][f % A_N] = action[(long)(row0 + f / A_N) * A_N + f % A_N];
    for (int f = tid; f < A_N * 256; f += 512)
        we1s[f >> 8][f & 255] = We1[f];
    if (tid < 256) be1s[tid] = be1[tid];
    __syncthreads();

    float acc[8][4];
#pragma unroll
    for (int i = 0; i < 8; i++)
#pragma unroll
        for (int j = 0; j < 4; j++) acc[i][j] = 0.0f;

    for (int k0 = 0; k0 < H_N; k0 += 32) {
        // compute h1 tile (enc1 chain, PROTECTED bits)
        for (int f = tid; f < 1024; f += 512) {
            int r = f >> 3, k4 = (f & 7) * 4;
#pragma unroll
            for (int j = 0; j < 4; j++) {
                int k = k0 + k4 + j;
                float a0 = be1s[k];
#pragma unroll
                for (int a = 0; a < A_N; a++) a0 = fmaf(acts[r][a], we1s[a][k], a0);
                As[k4 + j][r] = fmaxf(a0, 0.0f);
            }
        }
        for (int f = tid; f < 1024; f += 512) {
            int kr = f >> 5, c4 = (f & 31) * 4;
            *(float4*)&Bs[kr][c4] = *(const float4*)&W[(long)(k0 + kr) * H_N + col0 + c4];
        }
        __syncthreads();
#pragma unroll
        for (int kk = 0; kk < 32; kk++) {
            float4 a0 = *(const float4*)&As[kk][ty * 8];
            float4 a1 = *(const float4*)&As[kk][ty * 8 + 4];
            float2 b0 = *(const float2*)&Bs[kk][tx * 2];
            float2 b1 = *(const float2*)&Bs[kk][64 + tx * 2];
            float av[8] = {a0.x, a0.y, a0.z, a0.w, a1.x, a1.y, a1.z, a1.w};
            float bv[4] = {b0.x, b0.y, b1.x, b1.y};
#pragma unroll
            for (int i = 0; i < 8; i++)
#pragma unroll
                for (int j = 0; j < 4; j++)
                    acc[i][j] = fmaf(av[i], bv[j], acc[i][j]);
        }
        __syncthreads();
    }
#pragma unroll
    for (int i = 0; i < 8; i++) {
        long r = row0 + ty * 8 + i;
        int c0 = col0 + tx * 2;
        int c1 = col0 + 64 + tx * 2;
        float2 o0, o1;
        o0.x = fmaxf(acc[i][0] + bias[c0 + 0], 0.0f);
        o0.y = fmaxf(acc[i][1] + bias[c0 + 1], 0.0f);
        o1.x = fmaxf(acc[i][2] + bias[c1 + 0], 0.0f);
        o1.y = fmaxf(acc[i][3] + bias[c1 + 1], 0.0f);
        *(float2*)&Omat[r * H_N + c0] = o0;
        *(float2*)&Omat[r * H_N + c1] = o1;
    }
}

// ---------------- encoder fp32 GEMM (enc3): 512 threads, 128x128 tile (R21 config) --------
// (z bits PROTECTED: one fmaf per k per C element, k ascending; one thread per C element.)
template<int RELU, int SPLITZ>
__global__ __launch_bounds__(512, 2) void gemm_rt(const float* __restrict__ Amat,
    const float* __restrict__ W, const float* __restrict__ bias,
    float* __restrict__ Omat, int Kdim, int N,
    short* __restrict__ OhS, short* __restrict__ OlS)
{
    __shared__ float As[32][132];   // k-major: As[k][row]
    __shared__ float Bs[32][132];   // k-major: Bs[k][col]
    int tid = threadIdx.x;          // 0..511
    int tx = tid & 31, ty = tid >> 5;
    int bid = blockIdx.y * gridDim.x + blockIdx.x;
    int by = bid % gridDim.y;
    int bx = bid / gridDim.y;
    int row0 = by * 128;
    int col0 = bx * 128;
    float acc[8][4];
#pragma unroll
    for (int i = 0; i < 8; i++)
#pragma unroll
        for (int j = 0; j < 4; j++) acc[i][j] = 0.0f;

    for (int k0 = 0; k0 < Kdim; k0 += 32) {
        for (int f = tid; f < 1024; f += 512) {
            int r = f >> 3, k4 = (f & 7) * 4;
            float4 v = *(const float4*)&Amat[(long)(row0 + r) * Kdim + k0 + k4];
            As[k4 + 0][r] = v.x; As[k4 + 1][r] = v.y; As[k4 + 2][r] = v.z; As[k4 + 3][r] = v.w;
        }
        for (int f = tid; f < 1024; f += 512) {
            int kr = f >> 5, c4 = (f & 31) * 4;
            *(float4*)&Bs[kr][c4] = *(const float4*)&W[(long)(k0 + kr) * N + col0 + c4];
        }
        __syncthreads();
#pragma unroll
        for (int kk = 0; kk < 32; kk++) {
            float4 a0 = *(const float4*)&As[kk][ty * 8];
            float4 a1 = *(const float4*)&As[kk][ty * 8 + 4];
            float2 b0 = *(const float2*)&Bs[kk][tx * 2];
            float2 b1 = *(const float2*)&Bs[kk][64 + tx * 2];
            float av[8] = {a0.x, a0.y, a0.z, a0.w, a1.x, a1.y, a1.z, a1.w};
            float bv[4] = {b0.x, b0.y, b1.x, b1.y};
#pragma unroll
            for (int i = 0; i < 8; i++)
#pragma unroll
                for (int j = 0; j < 4; j++)
                    acc[i][j] = fmaf(av[i], bv[j], acc[i][j]);
        }
        __syncthreads();
    }
#pragma unroll
    for (int i = 0; i < 8; i++) {
        long r = row0 + ty * 8 + i;
        int c0 = col0 + tx * 2;
        int c1 = col0 + 64 + tx * 2;
        float2 o0, o1;
        o0.x = acc[i][0] + bias[c0 + 0];
        o0.y = acc[i][1] + bias[c0 + 1];
        o1.x = acc[i][2] + bias[c1 + 0];
        o1.y = acc[i][3] + bias[c1 + 1];
        if (RELU) {
            o0.x = fmaxf(o0.x, 0.0f); o0.y = fmaxf(o0.y, 0.0f);
            o1.x = fmaxf(o1.x, 0.0f); o1.y = fmaxf(o1.y, 0.0f);
        }
        *(float2*)&Omat[r * N + c0] = o0;
        *(float2*)&Omat[r * N + c1] = o1;
        if (SPLITZ) {   // fused z hi/lo split (identical bits to the old split_kernel)
            short2 h0, l0, h1, l1;
            h0.x = (short)f2bf(o0.x); l0.x = (short)f2bf(o0.x - bf2f(h0.x));
            h0.y = (short)f2bf(o0.y); l0.y = (short)f2bf(o0.y - bf2f(h0.y));
            h1.x = (short)f2bf(o1.x); l1.x = (short)f2bf(o1.x - bf2f(h1.x));
            h1.y = (short)f2bf(o1.y); l1.y = (short)f2bf(o1.y - bf2f(h1.y));
            *(short2*)&OhS[r * N + c0] = h0;
            *(short2*)&OhS[r * N + c1] = h1;
            *(short2*)&OlS[r * N + c0] = l0;
            *(short2*)&OlS[r * N + c1] = l1;
        }
    }
}

// ---------------- VQ candidates: 32-code tiles, 4 independent MFMA chains (R17-validated) --
__global__ __launch_bounds__(256, 2) void vq_mfma(const short* __restrict__ zh,
    const short* __restrict__ zl, const short* __restrict__ eh, const short* __restrict__ el,
    const float* __restrict__ az2, const float* __restrict__ e2,
    float4* __restrict__ twq /* [B][CB_N] = (v1, i1-bits, v2, 0) */)
{
    __shared__ short ehs[2][32 * 136];
    __shared__ short els[2][32 * 136];
    int tid = threadIdx.x;
    int wave = tid >> 6, lane = tid & 63;
    int lo = lane & 15, hi = lane >> 4;
    int row0 = blockIdx.y * 64 + wave * 16;
    int code0 = blockIdx.x * CPC;

    bf16x8 ahf[4], alf[4];
#pragma unroll
    for (int ks = 0; ks < 4; ks++) {
        long o = (long)(row0 + lo) * D_N + ks * 32 + hi * 8;
        ahf[ks] = *(const bf16x8*)&zh[o];
        alf[ks] = *(const bf16x8*)&zl[o];
    }
    float az_r[4];
#pragma unroll
    for (int r = 0; r < 4; r++) az_r[r] = az2[row0 + hi * 4 + r];

    float v1[4], v2[4];
    int   i1[4];
#pragma unroll
    for (int r = 0; r < 4; r++) { v1[r] = v2[r] = 1e30f; i1[r] = 0; }

    {   // stage tile 0 into buf 0 (32 codes x 128 d, 2 units/thread/array)
#pragma unroll
        for (int u = 0; u < 2; u++) {
            int f = tid + u * 256;
            int scode = f >> 4, sq = f & 15;
            long g = (long)(code0 + scode) * D_N + sq * 8;
            *(bf16x8*)&ehs[0][scode * 136 + sq * 8] = *(const bf16x8*)&eh[g];
            *(bf16x8*)&els[0][scode * 136 + sq * 8] = *(const bf16x8*)&el[g];
        }
    }
    __syncthreads();

#pragma unroll 1
    for (int t = 0; t < CPC / 32; t++) {
        int buf = t & 1;
        bf16x8 nh[2], nl[2];
        bool more = (t + 1 < CPC / 32);
        if (more) {   // issue next-tile loads early (latency hides under MFMA)
#pragma unroll
            for (int u = 0; u < 2; u++) {
                int f = tid + u * 256;
                int scode = f >> 4, sq = f & 15;
                long g = (long)(code0 + (t + 1) * 32 + scode) * D_N + sq * 8;
                nh[u] = *(const bf16x8*)&eh[g];
                nl[u] = *(const bf16x8*)&el[g];
            }
        }
        int codeA = code0 + t * 32 + lo;          // cb=0 column
        int codeB = codeA + 16;                   // cb=1 column
        float e2A = e2[codeA];
        float e2B = e2[codeB];
        f32x4 a1A = {0.f, 0.f, 0.f, 0.f}, a2A = {0.f, 0.f, 0.f, 0.f};
        f32x4 a1B = {0.f, 0.f, 0.f, 0.f}, a2B = {0.f, 0.f, 0.f, 0.f};
#pragma unroll
        for (int ks = 0; ks < 4; ks++) {
            bf16x8 bhA = *(const bf16x8*)&ehs[buf][lo * 136 + ks * 32 + hi * 8];
            bf16x8 blA = *(const bf16x8*)&els[buf][lo * 136 + ks * 32 + hi * 8];
            bf16x8 bhB = *(const bf16x8*)&ehs[buf][(16 + lo) * 136 + ks * 32 + hi * 8];
            bf16x8 blB = *(const bf16x8*)&els[buf][(16 + lo) * 136 + ks * 32 + hi * 8];
            a1A = __builtin_amdgcn_mfma_f32_16x16x32_bf16(ahf[ks], bhA, a1A, 0, 0, 0);
            a1B = __builtin_amdgcn_mfma_f32_16x16x32_bf16(ahf[ks], bhB, a1B, 0, 0, 0);
            a2A = __builtin_amdgcn_mfma_f32_16x16x32_bf16(ahf[ks], blA, a2A, 0, 0, 0);
            a2B = __builtin_amdgcn_mfma_f32_16x16x32_bf16(ahf[ks], blB, a2B, 0, 0, 0);
            a1A = __builtin_amdgcn_mfma_f32_16x16x32_bf16(alf[ks], bhA, a1A, 0, 0, 0);
            a1B = __builtin_amdgcn_mfma_f32_16x16x32_bf16(alf[ks], bhB, a1B, 0, 0, 0);
        }
#pragma unroll
        for (int r = 0; r < 4; r++) {          // cb=0 first: in-lane codes ascend
            float dot = a1A[r] + a2A[r];
            float s = (az_r[r] + e2A) - 2.0f * dot;
            bool lt = s < v1[r];               // strict: first-min on ties
            i1[r] = lt ? codeA : i1[r];
            v2[r] = fminf(v2[r], fmaxf(v1[r], s));
            v1[r] = fminf(v1[r], s);
        }
#pragma unroll
        for (int r = 0; r < 4; r++) {
            float dot = a1B[r] + a2B[r];
            float s = (az_r[r] + e2B) - 2.0f * dot;
            bool lt = s < v1[r];
            i1[r] = lt ? codeB : i1[r];
            v2[r] = fminf(v2[r], fmaxf(v1[r], s));
            v1[r] = fminf(v1[r], s);
        }
        if (more) {   // write-late into alternate buffer
#pragma unroll
            for (int u = 0; u < 2; u++) {
                int f = tid + u * 256;
                int scode = f >> 4, sq = f & 15;
                *(bf16x8*)&ehs[buf ^ 1][scode * 136 + sq * 8] = nh[u];
                *(bf16x8*)&els[buf ^ 1][scode * 136 + sq * 8] = nl[u];
            }
        }
        __syncthreads();
    }

    // 16-lane butterfly: lex-min (v1,i1), v2 = min(v2a, v2b, max(v1a, v1b))
#pragma unroll
    for (int m = 1; m < 16; m <<= 1) {
#pragma unroll
        for (int r = 0; r < 4; r++) {
            float ov1 = __shfl_xor(v1[r], m, 16);
            int   oi1 = __shfl_xor(i1[r], m, 16);
            float ov2 = __shfl_xor(v2[r], m, 16);
            v2[r] = fminf(fminf(v2[r], ov2), fmaxf(v1[r], ov1));
            bool bl = (ov1 < v1[r]) || (ov1 == v1[r] && oi1 < i1[r]);
            v1[r] = bl ? ov1 : v1[r];
            i1[r] = bl ? oi1 : i1[r];
        }
    }
    if (lo == 0) {
#pragma unroll
        for (int r = 0; r < 4; r++) {
            twq[(long)(row0 + hi * 4 + r) * CB_N + blockIdx.x] =
                make_float4(v1[r], __int_as_float(i1[r]), v2[r], 0.0f);
        }
    }
}

// ---------------- pick: exact refine of the CB_N candidates + cert + fused vq-loss -------
// R21 change: float4 loads (same addresses/values; fmaf chain order IDENTICAL -> same bits;
// mirrors the proven vq_fallback pattern). Adjacent threads share the z row.
__global__ __launch_bounds__(256) void vq_pick(const float4* __restrict__ twq,
    const float* __restrict__ z, const float* __restrict__ emb,
    const float* __restrict__ az2, const float* __restrict__ e2,
    int* __restrict__ idxI, float* __restrict__ outIdx,
    int* __restrict__ flaglist, int* __restrict__ flagcnt,
    unsigned long long* __restrict__ key, float* __restrict__ vqp)
{
    __shared__ float red[256];
    int tid = threadIdx.x;
    long g = (long)blockIdx.x * 256 + tid;
    int r = (int)(g >> 1), which = (int)(g & 1);
    float4 t = twq[(long)r * CB_N + which];
    int c = __float_as_int(t.y);
    const float4* z4p = (const float4*)(z + (long)r * D_N);
    const float4* e4p = (const float4*)(emb + (long)c * D_N);
    float C = 0.0f;
#pragma unroll
    for (int q = 0; q < 32; q++) {             // PROTECTED chain (order unchanged)
        float4 zv = z4p[q];
        float4 ev = e4p[q];
        C = fmaf(zv.x, ev.x, C);
        C = fmaf(zv.y, ev.y, C);
        C = fmaf(zv.z, ev.z, C);
        C = fmaf(zv.w, ev.w, C);
    }
    float d2 = (az2[r] + e2[c]) - 2.0f * C;
    float od2 = __shfl_xor(d2, 1, 64);
    int   oc  = __shfl_xor(c, 1, 64);
    float ov2 = __shfl_xor(t.z, 1, 64);
    float bd = d2; int bi = c;
    if (od2 < bd || (od2 == bd && oc < bi)) { bd = od2; bi = oc; }
    float v2min = fminf(t.z, ov2);
    float contrib = 0.0f;
    if (which == 0) {
        idxI[r] = bi;
        outIdx[r] = (float)bi;
        key[r] = 0xFFFFFFFFFFFFFFFFull;
        if (v2min <= bd + MU_CERT) {
            int s = atomicAdd(flagcnt, 1);
            flaglist[s] = r;
        }
        contrib = bd;   // exact ||z-q||^2 for this row (flagged-row error negligible)
    }
    red[tid] = contrib;
    __syncthreads();
    for (int o = 128; o > 0; o >>= 1) { if (tid < o) red[tid] += red[tid + o]; __syncthreads(); }
    if (tid == 0) vqp[blockIdx.x] = red[0];
}

// ---------------- exact scan for flagged rows: one BLOCK per (row, 256-code chunk) --------
__global__ __launch_bounds__(256) void vq_fallback(const float* __restrict__ z,
    const float* __restrict__ emb, const float* __restrict__ az2, const float* __restrict__ e2,
    const int* __restrict__ flaglist, const int* __restrict__ flagcnt,
    unsigned long long* __restrict__ key)
{
    __shared__ float zs[128];
    __shared__ unsigned long long rk[256];
    int n = *flagcnt;
    int tid = threadIdx.x;
    long total = (long)n * 8;
    for (long w = blockIdx.x; w < total; w += gridDim.x) {
        __syncthreads();
        int r = flaglist[w >> 3];
        int chunk = (int)(w & 7);
        if (tid < 32) *(float4*)&zs[tid * 4] = *(const float4*)&z[(long)r * D_N + tid * 4];
        __syncthreads();
        int code = chunk * 256 + tid;
        const float4* er = (const float4*)&emb[(long)code * D_N];
        float C = 0.0f;
#pragma unroll
        for (int q = 0; q < 32; q++) {         // EXACT ascending-d chain (PROTECTED)
            float4 e4 = er[q];
            float4 z4 = *(const float4*)&zs[q * 4];
            C = fmaf(z4.x, e4.x, C);
            C = fmaf(z4.y, e4.y, C);
            C = fmaf(z4.z, e4.z, C);
            C = fmaf(z4.w, e4.w, C);
        }
        float d2 = (az2[r] + e2[code]) - 2.0f * C;
        unsigned ub = __float_as_uint(d2);
        ub ^= (ub >> 31) ? 0xFFFFFFFFu : 0x80000000u;
        rk[tid] = ((unsigned long long)ub << 32) | (unsigned)code;
        __syncthreads();
        for (int o = 128; o > 0; o >>= 1) {
            if (tid < o) rk[tid] = rk[tid] < rk[tid + o] ? rk[tid] : rk[tid + o];
            __syncthreads();
        }
        if (tid == 0) atomicMin(&key[r], rk[0]);
    }
}

__global__ __launch_bounds__(256) void vq_finalize(const int* __restrict__ flaglist,
    const int* __restrict__ flagcnt, const unsigned long long* __restrict__ key,
    int* __restrict__ idxI, float* __restrict__ outIdx)
{
    int i = blockIdx.x * 256 + threadIdx.x;
    if (i < *flagcnt) {
        int r = flaglist[i];
        int c = (int)(key[r] & 0xFFFFFFFFull);
        idxI[r] = c;
        outIdx[r] = (float)c;
    }
}

// ---------------- decoder GEMM via bf16-split MFMA (R13-validated) ----------
template<int KD, int GATHER, int SPLITOUT>
__global__ __launch_bounds__(256, 2) void gemm_mfma(
    const short* __restrict__ Ah, const short* __restrict__ Al,
    const short* __restrict__ BhT, const short* __restrict__ BlT,   // [n][KD]
    const float* __restrict__ bias, const int* __restrict__ gidx,
    float* __restrict__ OutF, short* __restrict__ OutH, short* __restrict__ OutL)
{
    constexpr int KS = KD / 32;
    constexpr int LDB = KD + 8;
    __shared__ short Bh[64 * LDB];
    __shared__ short Bl[64 * LDB];
    int tid = threadIdx.x;
    int wave = tid >> 6, lane = tid & 63;
    int lo = lane & 15, hi = lane >> 4;
    int row0 = blockIdx.y * 64 + wave * 16;
    int c0 = blockIdx.x * 64;

    for (int f = tid; f < 64 * (KD / 8); f += 256) {
        int c = f / (KD / 8), q = f % (KD / 8);
        *(bf16x8*)&Bh[c * LDB + q * 8] = *(const bf16x8*)&BhT[(long)(c0 + c) * KD + q * 8];
        *(bf16x8*)&Bl[c * LDB + q * 8] = *(const bf16x8*)&BlT[(long)(c0 + c) * KD + q * 8];
    }
    int arow = row0 + lo;
    long abase = (GATHER ? (long)gidx[arow] : (long)arow) * KD;
    bf16x8 ah[KS], al[KS];
#pragma unroll
    for (int ks = 0; ks < KS; ks++) {
        ah[ks] = *(const bf16x8*)&Ah[abase + ks * 32 + hi * 8];
        al[ks] = *(const bf16x8*)&Al[abase + ks * 32 + hi * 8];
    }
    __syncthreads();

    f32x4 a1[4], a2[4];
#pragma unroll
    for (int g = 0; g < 4; g++) {
        a1[g] = (f32x4){0.f, 0.f, 0.f, 0.f};
        a2[g] = (f32x4){0.f, 0.f, 0.f, 0.f};
    }
#pragma unroll
    for (int g = 0; g < 4; g++) {
        int cb = (g * 16 + lo) * LDB;
#pragma unroll
        for (int ks = 0; ks < KS; ks++) {
            bf16x8 bh = *(const bf16x8*)&Bh[cb + ks * 32 + hi * 8];
            bf16x8 bl = *(const bf16x8*)&Bl[cb + ks * 32 + hi * 8];
            a1[g] = __builtin_amdgcn_mfma_f32_16x16x32_bf16(ah[ks], bh, a1[g], 0, 0, 0);
            a2[g] = __builtin_amdgcn_mfma_f32_16x16x32_bf16(ah[ks], bl, a2[g], 0, 0, 0);
            a1[g] = __builtin_amdgcn_mfma_f32_16x16x32_bf16(al[ks], bh, a1[g], 0, 0, 0);
        }
    }
#pragma unroll
    for (int g = 0; g < 4; g++) {
        int col = c0 + g * 16 + lo;
        float bv = bias[col];
#pragma unroll
        for (int r = 0; r < 4; r++) {
            long row = row0 + hi * 4 + r;
            float v = fmaxf((a1[g][r] + a2[g][r]) + bv, 0.0f);
            if (SPLITOUT) {
                unsigned short h = f2bf(v);
                OutH[row * 256 + col] = (short)h;
                OutL[row * 256 + col] = (short)f2bf(v - bf2f(h));
            } else {
                OutF[row * 256 + col] = v;
            }
        }
    }
}

// ---------------- head: recons = tanh(d2 @ Wh + bh), partial recon loss ----------------
__global__ __launch_bounds__(256) void head_kernel(const float* __restrict__ dbuf,
    const float* __restrict__ Wh, const float* __restrict__ bh,
    const float* __restrict__ action, float* __restrict__ outRec, float* __restrict__ part)
{
    __shared__ float WhS[H_N * A_N];
    __shared__ float red[256];
    int tid = threadIdx.x;
    for (int i = tid; i < H_N * A_N; i += 256) WhS[i] = Wh[i];
    __syncthreads();
    long t = (long)blockIdx.x * 256 + tid;
    int row = (int)(t / 6), col = (int)(t % 6);
    const float* dr = dbuf + (long)row * H_N;
    float acc = bh[col];
    for (int k = 0; k < H_N; k++) acc = fmaf(dr[k], WhS[k * 6 + col], acc);
    float rec = tanhf(acc);
    outRec[t] = rec;
    float diff = rec - action[t];
    red[tid] = diff * diff;
    __syncthreads();
    for (int o = 128; o > 0; o >>= 1) { if (tid < o) red[tid] += red[tid + o]; __syncthreads(); }
    if (tid == 0) part[blockIdx.x] = red[0];
}

// ---------------- finalize scalars ----------------
__global__ void final_kernel(const float* __restrict__ vqp, const float* __restrict__ recp,
                             float* __restrict__ out)
{
    if (threadIdx.x == 0 && blockIdx.x == 0) {
        double vs = 0.0;
        for (int i = 0; i < 256; i++) vs += (double)vqp[i];
        double rs = 0.0;
        for (int i = 0; i < 768; i++) rs += (double)recp[i];
        double m = vs / 4194304.0;           // B*D
        double vql = 1.25 * m;               // beta*commit + embed (forward-equal)
        double rl = rs / 196608.0;           // B*A
        out[0] = (float)(rl + vql);
        out[1] = (float)vql;
        out[2] = (float)rl;
    }
}

extern "C" void kernel_launch(void* const* d_in, const int* in_sizes, int n_in,
                              void* d_out, int out_size, void* d_ws, size_t ws_size,
                              hipStream_t stream)
{
    (void)in_sizes; (void)n_in; (void)out_size; (void)ws_size;
    const float* action = (const float*)d_in[0];
    const float* We1 = (const float*)d_in[1];
    const float* be1 = (const float*)d_in[2];
    const float* We2 = (const float*)d_in[3];
    const float* be2 = (const float*)d_in[4];
    const float* We3 = (const float*)d_in[5];
    const float* be3 = (const float*)d_in[6];
    const float* emb = (const float*)d_in[7];
    const float* Wd1 = (const float*)d_in[8];
    const float* bd1 = (const float*)d_in[9];
    const float* Wd2 = (const float*)d_in[10];
    const float* bd2 = (const float*)d_in[11];
    const float* Wh  = (const float*)d_in[12];
    const float* bh  = (const float*)d_in[13];
    float* out = (float*)d_out;

    // workspace layout (~85 MB):
    //   h1 region (B*H f32): zh/zl/eh/el (VQ) -> dec2 f32 output  (h1 never materialized)
    //   h2 region (B*H f32): enc-h2 -> twq/flaglist/flagcnt -> h1h/h1l (dec)
    //   z   (B*D f32)
    //   tail: az2(B) e2(K) idxI(B) vqp(256) recp(768) key(B u64) Wd splits
    float* h1 = (float*)d_ws;
    float* h2 = h1 + (long)B_N * H_N;
    float* z  = h2 + (long)B_N * H_N;
    float* az2 = z + (long)B_N * D_N;
    float* e2  = az2 + B_N;
    int*   idxI = (int*)(e2 + K_N);
    float* vqp  = (float*)(idxI + B_N);
    float* recp = vqp + 512;
    unsigned long long* key = (unsigned long long*)(recp + 768);
    short* Wd1hT = (short*)(key + B_N);               // 128*256
    short* Wd1lT = Wd1hT + D_N * H_N;
    short* Wd2hT = Wd1lT + D_N * H_N;                 // 256*256
    short* Wd2lT = Wd2hT + H_N * H_N;

    short* zh = (short*)h1;                 // 8.4 MB (written by gemm3 epilogue)
    short* zl = zh + (long)B_N * D_N;       // 8.4 MB
    short* eh = zl + (long)B_N * D_N;       // 0.5 MB (written by prep)
    short* el = eh + (long)K_N * D_N;       // 0.5 MB
    float4* twq = (float4*)h2;              // B*CB_N float4 = 1 MB
    int* flaglist = (int*)(twq + (long)B_N * CB_N);
    int* flagcnt  = flaglist + B_N;
    short* h1h = (short*)h2;                // dec h1 split (written AFTER vq_finalize)
    short* h1l = h1h + (long)B_N * H_N;
    float* d2f = h1;                        // dec2 f32 out (written AFTER dec1)

    // encoder (protected fp32 chains; enc1 fused into enc2; gemm3 also emits zh/zl)
    gemm_enc2<<<dim3(2, B_N / 128), 512, 0, stream>>>(action, We1, be1, We2, be2, h2);
    gemm_rt<0, 1><<<dim3(1, B_N / 128), 512, 0, stream>>>(h2, We3, be3, z, H_N, D_N,
                                                          zh, zl);

    // fused prep: embsplit + rowsum + splitT(Wd1) + splitT(Wd2) + flagcnt reset (1 launch)
    prep_kernel<<<520, 256, 0, stream>>>(emb, e2, eh, el, z, az2,
                                         Wd1, Wd1hT, Wd1lT, Wd2, Wd2hT, Wd2lT, flagcnt);

    // VQ: MFMA candidates -> exact refine + cert + fused loss -> chunked exact scan
    vq_mfma<<<dim3(CB_N, B_N / 64), 256, 0, stream>>>(zh, zl, eh, el, az2, e2, twq);
    vq_pick<<<(B_N * 2) / 256, 256, 0, stream>>>(twq, z, emb, az2, e2, idxI, out + 3,
                                                 flaglist, flagcnt, key, vqp);
    vq_fallback<<<4096, 256, 0, stream>>>(z, emb, az2, e2, flaglist, flagcnt, key);
    vq_finalize<<<B_N / 256, 256, 0, stream>>>(flaglist, flagcnt, key, idxI, out + 3);

    // decoder via MFMA (R13-validated)
    gemm_mfma<D_N, 1, 1><<<dim3(H_N / 64, B_N / 64), 256, 0, stream>>>(
        eh, el, Wd1hT, Wd1lT, bd1, idxI, nullptr, h1h, h1l);
    gemm_mfma<H_N, 0, 0><<<dim3(H_N / 64, B_N / 64), 256, 0, stream>>>(
        h1h, h1l, Wd2hT, Wd2lT, bd2, nullptr, d2f, nullptr, nullptr);

    // head + losses
    head_kernel<<<(B_N * A_N) / 256, 256, 0, stream>>>(d2f, Wh, bh, action, out + 3 + B_N, recp);
    final_kernel<<<1, 64, 0, stream>>>(vqp, recp, out);
}

// Round 23
// 287.374 us; speedup vs baseline: 1.0628x; 1.0278x over previous
//
#include <hip/hip_runtime.h>
#include <math.h>

#define B_N 32768
#define A_N 6
#define H_N 256
#define D_N 128
#define K_N 2048
#define MU_CERT 2e-8f   // >= 4x the bf16-split approx error bound (~5e-9)
#define CB_N 2          // code-dimension split of vq_mfma
#define CPC (K_N / CB_N)

typedef __attribute__((ext_vector_type(8))) short bf16x8;
typedef __attribute__((ext_vector_type(4))) float f32x4;

// Block compiler from contracting a*a into subsequent adds (np computes z*z array, then sums it)
__device__ __forceinline__ float sqf(float v) {
    float s = v * v;
    asm volatile("" : "+v"(s));
    return s;
}

// numpy pairwise_sum for n=128 contiguous fp32: 8 accumulators stride-8 + fixed 3-level tree.
// Bitwise replication of np.sum(x*x, axis=-1). PROTECTED SEMANTICS: do not alter the add order.
__device__ __forceinline__ float np_sumsq_128(const float* __restrict__ p)
{
    float r[8];
#pragma unroll
    for (int j = 0; j < 8; j++) r[j] = sqf(p[j]);
#pragma unroll
    for (int i = 8; i < 128; i += 8) {
#pragma unroll
        for (int j = 0; j < 8; j++) r[j] = r[j] + sqf(p[i + j]);
    }
    return ((r[0] + r[1]) + (r[2] + r[3])) + ((r[4] + r[5]) + (r[6] + r[7]));
}

// ---------------- bf16 hi/lo split helpers ----------------
__device__ __forceinline__ unsigned short f2bf(float x) {
    unsigned u = __float_as_uint(x);
    u += 0x7fffu + ((u >> 16) & 1u);
    return (unsigned short)(u >> 16);
}
__device__ __forceinline__ float bf2f(unsigned short h) {
    return __uint_as_float(((unsigned)h) << 16);
}

// ---------------- fused prep: embsplit + rowsum + splitT(Wd1) + splitT(Wd2) + flag reset --
__global__ __launch_bounds__(256) void prep_kernel(
    const float* __restrict__ emb, float* __restrict__ e2,
    short* __restrict__ eh, short* __restrict__ el,
    const float* __restrict__ z, float* __restrict__ az2,
    const float* __restrict__ Wd1, short* __restrict__ Wd1hT, short* __restrict__ Wd1lT,
    const float* __restrict__ Wd2, short* __restrict__ Wd2hT, short* __restrict__ Wd2lT,
    int* __restrict__ flagcnt)
{
    int blk = blockIdx.x;
    int tid = threadIdx.x;
    if (blk == 0 && tid == 0) *flagcnt = 0;
    if (blk < 8) {
        // ---- embsplit: e2[k] np-exact + emb hi/lo split ----
        int k = blk * 256 + tid;
        const float* p = emb + (long)k * D_N;
        float r[8];
#pragma unroll
        for (int i = 0; i < 128; i += 8) {
            float4 a = *(const float4*)&p[i];
            float4 b = *(const float4*)&p[i + 4];
            float v[8] = {a.x, a.y, a.z, a.w, b.x, b.y, b.z, b.w};
            if (i == 0) {
#pragma unroll
                for (int j = 0; j < 8; j++) r[j] = sqf(v[j]);
            } else {
#pragma unroll
                for (int j = 0; j < 8; j++) r[j] = r[j] + sqf(v[j]);  // PROTECTED order
            }
            short4 h0, h1, l0, l1;
            h0.x = (short)f2bf(v[0]); l0.x = (short)f2bf(v[0] - bf2f(h0.x));
            h0.y = (short)f2bf(v[1]); l0.y = (short)f2bf(v[1] - bf2f(h0.y));
            h0.z = (short)f2bf(v[2]); l0.z = (short)f2bf(v[2] - bf2f(h0.z));
            h0.w = (short)f2bf(v[3]); l0.w = (short)f2bf(v[3] - bf2f(h0.w));
            h1.x = (short)f2bf(v[4]); l1.x = (short)f2bf(v[4] - bf2f(h1.x));
            h1.y = (short)f2bf(v[5]); l1.y = (short)f2bf(v[5] - bf2f(h1.y));
            h1.z = (short)f2bf(v[6]); l1.z = (short)f2bf(v[6] - bf2f(h1.z));
            h1.w = (short)f2bf(v[7]); l1.w = (short)f2bf(v[7] - bf2f(h1.w));
            *(short4*)&eh[(long)k * D_N + i] = h0;
            *(short4*)&eh[(long)k * D_N + i + 4] = h1;
            *(short4*)&el[(long)k * D_N + i] = l0;
            *(short4*)&el[(long)k * D_N + i + 4] = l1;
        }
        e2[k] = ((r[0] + r[1]) + (r[2] + r[3])) + ((r[4] + r[5]) + (r[6] + r[7]));
    } else if (blk < 136) {
        // ---- rowsum: az2[r] np-exact ----
        int r = (blk - 8) * 256 + tid;
        az2[r] = np_sumsq_128(z + (long)r * D_N);
    } else if (blk < 264) {
        // ---- splitT Wd1: [k][n] -> [n][128] ----
        int i = (blk - 136) * 256 + tid;
        int k = i >> 8;
        int n = i & 255;
        float v = Wd1[i];
        unsigned short h = f2bf(v);
        Wd1hT[(long)n * D_N + k] = (short)h;
        Wd1lT[(long)n * D_N + k] = (short)f2bf(v - bf2f(h));
    } else {
        // ---- splitT Wd2: [k][n] -> [n][256] ----
        int i = (blk - 264) * 256 + tid;
        int k = i >> 8;
        int n = i & 255;
        float v = Wd2[i];
        unsigned short h = f2bf(v);
        Wd2hT[(long)n * H_N + k] = (short)h;
        Wd2lT[(long)n * H_N + k] = (short)f2bf(v - bf2f(h));
    }
}

// ---------------- enc1+enc2 fused GEMM: 512 threads, 128x128 tile, 8x4/thread ------------
// (R22-validated: VALUBusy 72-74%, FETCH 1.5MB. PROTECTED enc1+enc2 chains.)
__global__ __launch_bounds__(512, 2) void gemm_enc2(const float* __restrict__ action,
    const float* __restrict__ We1, const float* __restrict__ be1,
    const float* __restrict__ W, const float* __restrict__ bias,
    float* __restrict__ Omat)
{
    __shared__ float As[32][132];   // k-major: As[k][row] (holds computed h1)
    __shared__ float Bs[32][132];   // k-major: Bs[k][col]
    __shared__ float acts[128][8];  // action rows (6 used, pad to 8)
    __shared__ float we1s[6][256];
    __shared__ float be1s[256];
    int tid = threadIdx.x;          // 0..511
    int tx = tid & 31, ty = tid >> 5;
    int bid = blockIdx.y * gridDim.x + blockIdx.x;
    int by = bid % gridDim.y;
    int bx = bid / gridDim.y;
    int row0 = by * 128;
    int col0 = bx * 128;

    // stage action rows + We1 + be1 once
    for (int f = tid; f < 128 * A_N; f += 512)
        acts[f / A_N][f % A_N] = action[(long)(row0 + f / A_N) * A_N + f % A_N];
    for (int f = tid; f < A_N * 256; f += 512)
        we1s[f >> 8][f & 255] = We1[f];
    if (tid < 256) be1s[tid] = be1[tid];
    __syncthreads();

    float acc[8][4];
#pragma unroll
    for (int i = 0; i < 8; i++)
#pragma unroll
        for (int j = 0; j < 4; j++) acc[i][j] = 0.0f;

    for (int k0 = 0; k0 < H_N; k0 += 32) {
        // compute h1 tile (enc1 chain, PROTECTED bits)
        for (int f = tid; f < 1024; f += 512) {
            int r = f >> 3, k4 = (f & 7) * 4;
#pragma unroll
            for (int j = 0; j < 4; j++) {
                int k = k0 + k4 + j;
                float a0 = be1s[k];
#pragma unroll
                for (int a = 0; a < A_N; a++) a0 = fmaf(acts[r][a], we1s[a][k], a0);
                As[k4 + j][r] = fmaxf(a0, 0.0f);
            }
        }
        for (int f = tid; f < 1024; f += 512) {
            int kr = f >> 5, c4 = (f & 31) * 4;
            *(float4*)&Bs[kr][c4] = *(const float4*)&W[(long)(k0 + kr) * H_N + col0 + c4];
        }
        __syncthreads();
#pragma unroll
        for (int kk = 0; kk < 32; kk++) {
            float4 a0 = *(const float4*)&As[kk][ty * 8];
            float4 a1 = *(const float4*)&As[kk][ty * 8 + 4];
            float2 b0 = *(const float2*)&Bs[kk][tx * 2];
            float2 b1 = *(const float2*)&Bs[kk][64 + tx * 2];
            float av[8] = {a0.x, a0.y, a0.z, a0.w, a1.x, a1.y, a1.z, a1.w};
            float bv[4] = {b0.x, b0.y, b1.x, b1.y};
#pragma unroll
            for (int i = 0; i < 8; i++)
#pragma unroll
                for (int j = 0; j < 4; j++)
                    acc[i][j] = fmaf(av[i], bv[j], acc[i][j]);
        }
        __syncthreads();
    }
#pragma unroll
    for (int i = 0; i < 8; i++) {
        long r = row0 + ty * 8 + i;
        int c0 = col0 + tx * 2;
        int c1 = col0 + 64 + tx * 2;
        float2 o0, o1;
        o0.x = fmaxf(acc[i][0] + bias[c0 + 0], 0.0f);
        o0.y = fmaxf(acc[i][1] + bias[c0 + 1], 0.0f);
        o1.x = fmaxf(acc[i][2] + bias[c1 + 0], 0.0f);
        o1.y = fmaxf(acc[i][3] + bias[c1 + 1], 0.0f);
        *(float2*)&Omat[r * H_N + c0] = o0;
        *(float2*)&Omat[r * H_N + c1] = o1;
    }
}

// ---------------- enc3 fp32 GEMM: 512 threads, 64x128 tile, 4x4/thread -------------------
// (z bits PROTECTED: one fmaf per k per C element, k ascending; one thread per C element.)
// R22 post-mortem: enc3 inherited the 128x128 shape -> 256 blocks = 1/CU = 8 waves/CU
// (grid-starved, same diagnosis as R15). 64-row tiles double the grid to 2 blocks/CU.
template<int RELU, int SPLITZ>
__global__ __launch_bounds__(512, 2) void gemm_rt(const float* __restrict__ Amat,
    const float* __restrict__ W, const float* __restrict__ bias,
    float* __restrict__ Omat, int Kdim, int N,
    short* __restrict__ OhS, short* __restrict__ OlS)
{
    __shared__ float As[32][68];    // k-major: As[k][row], 64 rows + pad
    __shared__ float Bs[32][132];   // k-major: Bs[k][col], 128 cols + pad
    int tid = threadIdx.x;          // 0..511
    int tx = tid & 31, ty = tid >> 5;   // tx: 32 col-groups, ty: 16 row-groups (4 rows each)
    int row0 = blockIdx.y * 64;
    int col0 = blockIdx.x * 128;
    float acc[4][4];
#pragma unroll
    for (int i = 0; i < 4; i++)
#pragma unroll
        for (int j = 0; j < 4; j++) acc[i][j] = 0.0f;

    for (int k0 = 0; k0 < Kdim; k0 += 32) {
        {   // stage A: 64 rows x 32 k = 512 float4, 1/thread
            int r = tid >> 3, k4 = (tid & 7) * 4;
            float4 v = *(const float4*)&Amat[(long)(row0 + r) * Kdim + k0 + k4];
            As[k4 + 0][r] = v.x; As[k4 + 1][r] = v.y; As[k4 + 2][r] = v.z; As[k4 + 3][r] = v.w;
        }
        for (int f = tid; f < 1024; f += 512) {   // stage B: 32 k x 128 cols
            int kr = f >> 5, c4 = (f & 31) * 4;
            *(float4*)&Bs[kr][c4] = *(const float4*)&W[(long)(k0 + kr) * N + col0 + c4];
        }
        __syncthreads();
#pragma unroll
        for (int kk = 0; kk < 32; kk++) {
            float4 a0 = *(const float4*)&As[kk][ty * 4];
            float2 b0 = *(const float2*)&Bs[kk][tx * 2];
            float2 b1 = *(const float2*)&Bs[kk][64 + tx * 2];
            float av[4] = {a0.x, a0.y, a0.z, a0.w};
            float bv[4] = {b0.x, b0.y, b1.x, b1.y};
#pragma unroll
            for (int i = 0; i < 4; i++)
#pragma unroll
                for (int j = 0; j < 4; j++)
                    acc[i][j] = fmaf(av[i], bv[j], acc[i][j]);
        }
        __syncthreads();
    }
#pragma unroll
    for (int i = 0; i < 4; i++) {
        long r = row0 + ty * 4 + i;
        int c0 = col0 + tx * 2;
        int c1 = col0 + 64 + tx * 2;
        float2 o0, o1;
        o0.x = acc[i][0] + bias[c0 + 0];
        o0.y = acc[i][1] + bias[c0 + 1];
        o1.x = acc[i][2] + bias[c1 + 0];
        o1.y = acc[i][3] + bias[c1 + 1];
        if (RELU) {
            o0.x = fmaxf(o0.x, 0.0f); o0.y = fmaxf(o0.y, 0.0f);
            o1.x = fmaxf(o1.x, 0.0f); o1.y = fmaxf(o1.y, 0.0f);
        }
        *(float2*)&Omat[r * N + c0] = o0;
        *(float2*)&Omat[r * N + c1] = o1;
        if (SPLITZ) {   // fused z hi/lo split (identical bits to the old split_kernel)
            short2 h0, l0, h1, l1;
            h0.x = (short)f2bf(o0.x); l0.x = (short)f2bf(o0.x - bf2f(h0.x));
            h0.y = (short)f2bf(o0.y); l0.y = (short)f2bf(o0.y - bf2f(h0.y));
            h1.x = (short)f2bf(o1.x); l1.x = (short)f2bf(o1.x - bf2f(h1.x));
            h1.y = (short)f2bf(o1.y); l1.y = (short)f2bf(o1.y - bf2f(h1.y));
            *(short2*)&OhS[r * N + c0] = h0;
            *(short2*)&OhS[r * N + c1] = h1;
            *(short2*)&OlS[r * N + c0] = l0;
            *(short2*)&OlS[r * N + c1] = l1;
        }
    }
}

// ---------------- VQ candidates: 32-code tiles, 4 independent MFMA chains (R17-validated) --
__global__ __launch_bounds__(256, 2) void vq_mfma(const short* __restrict__ zh,
    const short* __restrict__ zl, const short* __restrict__ eh, const short* __restrict__ el,
    const float* __restrict__ az2, const float* __restrict__ e2,
    float4* __restrict__ twq /* [B][CB_N] = (v1, i1-bits, v2, 0) */)
{
    __shared__ short ehs[2][32 * 136];
    __shared__ short els[2][32 * 136];
    int tid = threadIdx.x;
    int wave = tid >> 6, lane = tid & 63;
    int lo = lane & 15, hi = lane >> 4;
    int row0 = blockIdx.y * 64 + wave * 16;
    int code0 = blockIdx.x * CPC;

    bf16x8 ahf[4], alf[4];
#pragma unroll
    for (int ks = 0; ks < 4; ks++) {
        long o = (long)(row0 + lo) * D_N + ks * 32 + hi * 8;
        ahf[ks] = *(const bf16x8*)&zh[o];
        alf[ks] = *(const bf16x8*)&zl[o];
    }
    float az_r[4];
#pragma unroll
    for (int r = 0; r < 4; r++) az_r[r] = az2[row0 + hi * 4 + r];

    float v1[4], v2[4];
    int   i1[4];
#pragma unroll
    for (int r = 0; r < 4; r++) { v1[r] = v2[r] = 1e30f; i1[r] = 0; }

    {   // stage tile 0 into buf 0 (32 codes x 128 d, 2 units/thread/array)
#pragma unroll
        for (int u = 0; u < 2; u++) {
            int f = tid + u * 256;
            int scode = f >> 4, sq = f & 15;
            long g = (long)(code0 + scode) * D_N + sq * 8;
            *(bf16x8*)&ehs[0][scode * 136 + sq * 8] = *(const bf16x8*)&eh[g];
            *(bf16x8*)&els[0][scode * 136 + sq * 8] = *(const bf16x8*)&el[g];
        }
    }
    __syncthreads();

#pragma unroll 1
    for (int t = 0; t < CPC / 32; t++) {
        int buf = t & 1;
        bf16x8 nh[2], nl[2];
        bool more = (t + 1 < CPC / 32);
        if (more) {   // issue next-tile loads early (latency hides under MFMA)
#pragma unroll
            for (int u = 0; u < 2; u++) {
                int f = tid + u * 256;
                int scode = f >> 4, sq = f & 15;
                long g = (long)(code0 + (t + 1) * 32 + scode) * D_N + sq * 8;
                nh[u] = *(const bf16x8*)&eh[g];
                nl[u] = *(const bf16x8*)&el[g];
            }
        }
        int codeA = code0 + t * 32 + lo;          // cb=0 column
        int codeB = codeA + 16;                   // cb=1 column
        float e2A = e2[codeA];
        float e2B = e2[codeB];
        f32x4 a1A = {0.f, 0.f, 0.f, 0.f}, a2A = {0.f, 0.f, 0.f, 0.f};
        f32x4 a1B = {0.f, 0.f, 0.f, 0.f}, a2B = {0.f, 0.f, 0.f, 0.f};
#pragma unroll
        for (int ks = 0; ks < 4; ks++) {
            bf16x8 bhA = *(const bf16x8*)&ehs[buf][lo * 136 + ks * 32 + hi * 8];
            bf16x8 blA = *(const bf16x8*)&els[buf][lo * 136 + ks * 32 + hi * 8];
            bf16x8 bhB = *(const bf16x8*)&ehs[buf][(16 + lo) * 136 + ks * 32 + hi * 8];
            bf16x8 blB = *(const bf16x8*)&els[buf][(16 + lo) * 136 + ks * 32 + hi * 8];
            a1A = __builtin_amdgcn_mfma_f32_16x16x32_bf16(ahf[ks], bhA, a1A, 0, 0, 0);
            a1B = __builtin_amdgcn_mfma_f32_16x16x32_bf16(ahf[ks], bhB, a1B, 0, 0, 0);
            a2A = __builtin_amdgcn_mfma_f32_16x16x32_bf16(ahf[ks], blA, a2A, 0, 0, 0);
            a2B = __builtin_amdgcn_mfma_f32_16x16x32_bf16(ahf[ks], blB, a2B, 0, 0, 0);
            a1A = __builtin_amdgcn_mfma_f32_16x16x32_bf16(alf[ks], bhA, a1A, 0, 0, 0);
            a1B = __builtin_amdgcn_mfma_f32_16x16x32_bf16(alf[ks], bhB, a1B, 0, 0, 0);
        }
#pragma unroll
        for (int r = 0; r < 4; r++) {          // cb=0 first: in-lane codes ascend
            float dot = a1A[r] + a2A[r];
            float s = (az_r[r] + e2A) - 2.0f * dot;
            bool lt = s < v1[r];               // strict: first-min on ties
            i1[r] = lt ? codeA : i1[r];
            v2[r] = fminf(v2[r], fmaxf(v1[r], s));
            v1[r] = fminf(v1[r], s);
        }
#pragma unroll
        for (int r = 0; r < 4; r++) {
            float dot = a1B[r] + a2B[r];
            float s = (az_r[r] + e2B) - 2.0f * dot;
            bool lt = s < v1[r];
            i1[r] = lt ? codeB : i1[r];
            v2[r] = fminf(v2[r], fmaxf(v1[r], s));
            v1[r] = fminf(v1[r], s);
        }
        if (more) {   // write-late into alternate buffer
#pragma unroll
            for (int u = 0; u < 2; u++) {
                int f = tid + u * 256;
                int scode = f >> 4, sq = f & 15;
                *(bf16x8*)&ehs[buf ^ 1][scode * 136 + sq * 8] = nh[u];
                *(bf16x8*)&els[buf ^ 1][scode * 136 + sq * 8] = nl[u];
            }
        }
        __syncthreads();
    }

    // 16-lane butterfly: lex-min (v1,i1), v2 = min(v2a, v2b, max(v1a, v1b))
#pragma unroll
    for (int m = 1; m < 16; m <<= 1) {
#pragma unroll
        for (int r = 0; r < 4; r++) {
            float ov1 = __shfl_xor(v1[r], m, 16);
            int   oi1 = __shfl_xor(i1[r], m, 16);
            float ov2 = __shfl_xor(v2[r], m, 16);
            v2[r] = fminf(fminf(v2[r], ov2), fmaxf(v1[r], ov1));
            bool bl = (ov1 < v1[r]) || (ov1 == v1[r] && oi1 < i1[r]);
            v1[r] = bl ? ov1 : v1[r];
            i1[r] = bl ? oi1 : i1[r];
        }
    }
    if (lo == 0) {
#pragma unroll
        for (int r = 0; r < 4; r++) {
            twq[(long)(row0 + hi * 4 + r) * CB_N + blockIdx.x] =
                make_float4(v1[r], __int_as_float(i1[r]), v2[r], 0.0f);
        }
    }
}

// ---------------- pick: exact refine of the CB_N candidates + cert + fused vq-loss -------
__global__ __launch_bounds__(256) void vq_pick(const float4* __restrict__ twq,
    const float* __restrict__ z, const float* __restrict__ emb,
    const float* __restrict__ az2, const float* __restrict__ e2,
    int* __restrict__ idxI, float* __restrict__ outIdx,
    int* __restrict__ flaglist, int* __restrict__ flagcnt,
    unsigned long long* __restrict__ key, float* __restrict__ vqp)
{
    __shared__ float red[256];
    int tid = threadIdx.x;
    long g = (long)blockIdx.x * 256 + tid;
    int r = (int)(g >> 1), which = (int)(g & 1);
    float4 t = twq[(long)r * CB_N + which];
    int c = __float_as_int(t.y);
    const float4* z4p = (const float4*)(z + (long)r * D_N);
    const float4* e4p = (const float4*)(emb + (long)c * D_N);
    float C = 0.0f;
#pragma unroll
    for (int q = 0; q < 32; q++) {             // PROTECTED chain (order unchanged)
        float4 zv = z4p[q];
        float4 ev = e4p[q];
        C = fmaf(zv.x, ev.x, C);
        C = fmaf(zv.y, ev.y, C);
        C = fmaf(zv.z, ev.z, C);
        C = fmaf(zv.w, ev.w, C);
    }
    float d2 = (az2[r] + e2[c]) - 2.0f * C;
    float od2 = __shfl_xor(d2, 1, 64);
    int   oc  = __shfl_xor(c, 1, 64);
    float ov2 = __shfl_xor(t.z, 1, 64);
    float bd = d2; int bi = c;
    if (od2 < bd || (od2 == bd && oc < bi)) { bd = od2; bi = oc; }
    float v2min = fminf(t.z, ov2);
    float contrib = 0.0f;
    if (which == 0) {
        idxI[r] = bi;
        outIdx[r] = (float)bi;
        key[r] = 0xFFFFFFFFFFFFFFFFull;
        if (v2min <= bd + MU_CERT) {
            int s = atomicAdd(flagcnt, 1);
            flaglist[s] = r;
        }
        contrib = bd;   // exact ||z-q||^2 for this row (flagged-row error negligible)
    }
    red[tid] = contrib;
    __syncthreads();
    for (int o = 128; o > 0; o >>= 1) { if (tid < o) red[tid] += red[tid + o]; __syncthreads(); }
    if (tid == 0) vqp[blockIdx.x] = red[0];
}

// ---------------- exact scan for flagged rows: one BLOCK per (row, 256-code chunk) --------
__global__ __launch_bounds__(256) void vq_fallback(const float* __restrict__ z,
    const float* __restrict__ emb, const float* __restrict__ az2, const float* __restrict__ e2,
    const int* __restrict__ flaglist, const int* __restrict__ flagcnt,
    unsigned long long* __restrict__ key)
{
    __shared__ float zs[128];
    __shared__ unsigned long long rk[256];
    int n = *flagcnt;
    int tid = threadIdx.x;
    long total = (long)n * 8;
    for (long w = blockIdx.x; w < total; w += gridDim.x) {
        __syncthreads();
        int r = flaglist[w >> 3];
        int chunk = (int)(w & 7);
        if (tid < 32) *(float4*)&zs[tid * 4] = *(const float4*)&z[(long)r * D_N + tid * 4];
        __syncthreads();
        int code = chunk * 256 + tid;
        const float4* er = (const float4*)&emb[(long)code * D_N];
        float C = 0.0f;
#pragma unroll
        for (int q = 0; q < 32; q++) {         // EXACT ascending-d chain (PROTECTED)
            float4 e4 = er[q];
            float4 z4 = *(const float4*)&zs[q * 4];
            C = fmaf(z4.x, e4.x, C);
            C = fmaf(z4.y, e4.y, C);
            C = fmaf(z4.z, e4.z, C);
            C = fmaf(z4.w, e4.w, C);
        }
        float d2 = (az2[r] + e2[code]) - 2.0f * C;
        unsigned ub = __float_as_uint(d2);
        ub ^= (ub >> 31) ? 0xFFFFFFFFu : 0x80000000u;
        rk[tid] = ((unsigned long long)ub << 32) | (unsigned)code;
        __syncthreads();
        for (int o = 128; o > 0; o >>= 1) {
            if (tid < o) rk[tid] = rk[tid] < rk[tid + o] ? rk[tid] : rk[tid + o];
            __syncthreads();
        }
        if (tid == 0) atomicMin(&key[r], rk[0]);
    }
}

__global__ __launch_bounds__(256) void vq_finalize(const int* __restrict__ flaglist,
    const int* __restrict__ flagcnt, const unsigned long long* __restrict__ key,
    int* __restrict__ idxI, float* __restrict__ outIdx)
{
    int i = blockIdx.x * 256 + threadIdx.x;
    if (i < *flagcnt) {
        int r = flaglist[i];
        int c = (int)(key[r] & 0xFFFFFFFFull);
        idxI[r] = c;
        outIdx[r] = (float)c;
    }
}

// ---------------- decoder GEMM via bf16-split MFMA (R13-validated) ----------
template<int KD, int GATHER, int SPLITOUT>
__global__ __launch_bounds__(256, 2) void gemm_mfma(
    const short* __restrict__ Ah, const short* __restrict__ Al,
    const short* __restrict__ BhT, const short* __restrict__ BlT,   // [n][KD]
    const float* __restrict__ bias, const int* __restrict__ gidx,
    float* __restrict__ OutF, short* __restrict__ OutH, short* __restrict__ OutL)
{
    constexpr int KS = KD / 32;
    constexpr int LDB = KD + 8;
    __shared__ short Bh[64 * LDB];
    __shared__ short Bl[64 * LDB];
    int tid = threadIdx.x;
    int wave = tid >> 6, lane = tid & 63;
    int lo = lane & 15, hi = lane >> 4;
    int row0 = blockIdx.y * 64 + wave * 16;
    int c0 = blockIdx.x * 64;

    for (int f = tid; f < 64 * (KD / 8); f += 256) {
        int c = f / (KD / 8), q = f % (KD / 8);
        *(bf16x8*)&Bh[c * LDB + q * 8] = *(const bf16x8*)&BhT[(long)(c0 + c) * KD + q * 8];
        *(bf16x8*)&Bl[c * LDB + q * 8] = *(const bf16x8*)&BlT[(long)(c0 + c) * KD + q * 8];
    }
    int arow = row0 + lo;
    long abase = (GATHER ? (long)gidx[arow] : (long)arow) * KD;
    bf16x8 ah[KS], al[KS];
#pragma unroll
    for (int ks = 0; ks < KS; ks++) {
        ah[ks] = *(const bf16x8*)&Ah[abase + ks * 32 + hi * 8];
        al[ks] = *(const bf16x8*)&Al[abase + ks * 32 + hi * 8];
    }
    __syncthreads();

    f32x4 a1[4], a2[4];
#pragma unroll
    for (int g = 0; g < 4; g++) {
        a1[g] = (f32x4){0.f, 0.f, 0.f, 0.f};
        a2[g] = (f32x4){0.f, 0.f, 0.f, 0.f};
    }
#pragma unroll
    for (int g = 0; g < 4; g++) {
        int cb = (g * 16 + lo) * LDB;
#pragma unroll
        for (int ks = 0; ks < KS; ks++) {
            bf16x8 bh = *(const bf16x8*)&Bh[cb + ks * 32 + hi * 8];
            bf16x8 bl = *(const bf16x8*)&Bl[cb + ks * 32 + hi * 8];
            a1[g] = __builtin_amdgcn_mfma_f32_16x16x32_bf16(ah[ks], bh, a1[g], 0, 0, 0);
            a2[g] = __builtin_amdgcn_mfma_f32_16x16x32_bf16(ah[ks], bl, a2[g], 0, 0, 0);
            a1[g] = __builtin_amdgcn_mfma_f32_16x16x32_bf16(al[ks], bh, a1[g], 0, 0, 0);
        }
    }
#pragma unroll
    for (int g = 0; g < 4; g++) {
        int col = c0 + g * 16 + lo;
        float bv = bias[col];
#pragma unroll
        for (int r = 0; r < 4; r++) {
            long row = row0 + hi * 4 + r;
            float v = fmaxf((a1[g][r] + a2[g][r]) + bv, 0.0f);
            if (SPLITOUT) {
                unsigned short h = f2bf(v);
                OutH[row * 256 + col] = (short)h;
                OutL[row * 256 + col] = (short)f2bf(v - bf2f(h));
            } else {
                OutF[row * 256 + col] = v;
            }
        }
    }
}

// ---------------- head: recons = tanh(d2 @ Wh + bh), partial recon loss ----------------
__global__ __launch_bounds__(256) void head_kernel(const float* __restrict__ dbuf,
    const float* __restrict__ Wh, const float* __restrict__ bh,
    const float* __restrict__ action, float* __restrict__ outRec, float* __restrict__ part)
{
    __shared__ float WhS[H_N * A_N];
    __shared__ float red[256];
    int tid = threadIdx.x;
    for (int i = tid; i < H_N * A_N; i += 256) WhS[i] = Wh[i];
    __syncthreads();
    long t = (long)blockIdx.x * 256 + tid;
    int row = (int)(t / 6), col = (int)(t % 6);
    const float* dr = dbuf + (long)row * H_N;
    float acc = bh[col];
    for (int k = 0; k < H_N; k++) acc = fmaf(dr[k], WhS[k * 6 + col], acc);
    float rec = tanhf(acc);
    outRec[t] = rec;
    float diff = rec - action[t];
    red[tid] = diff * diff;
    __syncthreads();
    for (int o = 128; o > 0; o >>= 1) { if (tid < o) red[tid] += red[tid + o]; __syncthreads(); }
    if (tid == 0) part[blockIdx.x] = red[0];
}

// ---------------- finalize scalars ----------------
__global__ void final_kernel(const float* __restrict__ vqp, const float* __restrict__ recp,
                             float* __restrict__ out)
{
    if (threadIdx.x == 0 && blockIdx.x == 0) {
        double vs = 0.0;
        for (int i = 0; i < 256; i++) vs += (double)vqp[i];
        double rs = 0.0;
        for (int i = 0; i < 768; i++) rs += (double)recp[i];
        double m = vs / 4194304.0;           // B*D
        double vql = 1.25 * m;               // beta*commit + embed (forward-equal)
        double rl = rs / 196608.0;           // B*A
        out[0] = (float)(rl + vql);
        out[1] = (float)vql;
        out[2] = (float)rl;
    }
}

extern "C" void kernel_launch(void* const* d_in, const int* in_sizes, int n_in,
                              void* d_out, int out_size, void* d_ws, size_t ws_size,
                              hipStream_t stream)
{
    (void)in_sizes; (void)n_in; (void)out_size; (void)ws_size;
    const float* action = (const float*)d_in[0];
    const float* We1 = (const float*)d_in[1];
    const float* be1 = (const float*)d_in[2];
    const float* We2 = (const float*)d_in[3];
    const float* be2 = (const float*)d_in[4];
    const float* We3 = (const float*)d_in[5];
    const float* be3 = (const float*)d_in[6];
    const float* emb = (const float*)d_in[7];
    const float* Wd1 = (const float*)d_in[8];
    const float* bd1 = (const float*)d_in[9];
    const float* Wd2 = (const float*)d_in[10];
    const float* bd2 = (const float*)d_in[11];
    const float* Wh  = (const float*)d_in[12];
    const float* bh  = (const float*)d_in[13];
    float* out = (float*)d_out;

    // workspace layout (~85 MB):
    //   h1 region (B*H f32): zh/zl/eh/el (VQ) -> dec2 f32 output  (h1 never materialized)
    //   h2 region (B*H f32): enc-h2 -> twq/flaglist/flagcnt -> h1h/h1l (dec)
    //   z   (B*D f32)
    //   tail: az2(B) e2(K) idxI(B) vqp(256) recp(768) key(B u64) Wd splits
    float* h1 = (float*)d_ws;
    float* h2 = h1 + (long)B_N * H_N;
    float* z  = h2 + (long)B_N * H_N;
    float* az2 = z + (long)B_N * D_N;
    float* e2  = az2 + B_N;
    int*   idxI = (int*)(e2 + K_N);
    float* vqp  = (float*)(idxI + B_N);
    float* recp = vqp + 512;
    unsigned long long* key = (unsigned long long*)(recp + 768);
    short* Wd1hT = (short*)(key + B_N);               // 128*256
    short* Wd1lT = Wd1hT + D_N * H_N;
    short* Wd2hT = Wd1lT + D_N * H_N;                 // 256*256
    short* Wd2lT = Wd2hT + H_N * H_N;

    short* zh = (short*)h1;                 // 8.4 MB (written by gemm3 epilogue)
    short* zl = zh + (long)B_N * D_N;       // 8.4 MB
    short* eh = zl + (long)B_N * D_N;       // 0.5 MB (written by prep)
    short* el = eh + (long)K_N * D_N;       // 0.5 MB
    float4* twq = (float4*)h2;              // B*CB_N float4 = 1 MB
    int* flaglist = (int*)(twq + (long)B_N * CB_N);
    int* flagcnt  = flaglist + B_N;
    short* h1h = (short*)h2;                // dec h1 split (written AFTER vq_finalize)
    short* h1l = h1h + (long)B_N * H_N;
    float* d2f = h1;                        // dec2 f32 out (written AFTER dec1)

    // encoder (protected fp32 chains; enc1 fused into enc2; enc3 also emits zh/zl)
    gemm_enc2<<<dim3(2, B_N / 128), 512, 0, stream>>>(action, We1, be1, We2, be2, h2);
    gemm_rt<0, 1><<<dim3(1, B_N / 64), 512, 0, stream>>>(h2, We3, be3, z, H_N, D_N,
                                                         zh, zl);

    // fused prep: embsplit + rowsum + splitT(Wd1) + splitT(Wd2) + flagcnt reset (1 launch)
    prep_kernel<<<520, 256, 0, stream>>>(emb, e2, eh, el, z, az2,
                                         Wd1, Wd1hT, Wd1lT, Wd2, Wd2hT, Wd2lT, flagcnt);

    // VQ: MFMA candidates -> exact refine + cert + fused loss -> chunked exact scan
    vq_mfma<<<dim3(CB_N, B_N / 64), 256, 0, stream>>>(zh, zl, eh, el, az2, e2, twq);
    vq_pick<<<(B_N * 2) / 256, 256, 0, stream>>>(twq, z, emb, az2, e2, idxI, out + 3,
                                                 flaglist, flagcnt, key, vqp);
    vq_fallback<<<4096, 256, 0, stream>>>(z, emb, az2, e2, flaglist, flagcnt, key);
    vq_finalize<<<B_N / 256, 256, 0, stream>>>(flaglist, flagcnt, key, idxI, out + 3);

    // decoder via MFMA (R13-validated)
    gemm_mfma<D_N, 1, 1><<<dim3(H_N / 64, B_N / 64), 256, 0, stream>>>(
        eh, el, Wd1hT, Wd1lT, bd1, idxI, nullptr, h1h, h1l);
    gemm_mfma<H_N, 0, 0><<<dim3(H_N / 64, B_N / 64), 256, 0, stream>>>(
        h1h, h1l, Wd2hT, Wd2lT, bd2, nullptr, d2f, nullptr, nullptr);

    // head + losses
    head_kernel<<<(B_N * A_N) / 256, 256, 0, stream>>>(d2f, Wh, bh, action, out + 3 + B_N, recp);
    final_kernel<<<1, 64, 0, stream>>>(vqp, recp, out);
}